// Round 1
// baseline (1765.919 us; speedup 1.0000x reference)
//
#include <hip/hip_runtime.h>
#include <stdint.h>

#define Bn 64
#define Tn 400
#define Hn 512
#define En 256
#define Vn 50000
#define NOOVn 100
#define TPn 50
#define H2n 1024
#define Mn (Bn*Tn)        // 25600
#define VEXTn (Vn+NOOVn)  // 50100

typedef __bf16 bf16x8 __attribute__((ext_vector_type(8)));
typedef float  f32x4  __attribute__((ext_vector_type(4)));

__device__ __forceinline__ float sigf(float x){ return 1.0f/(1.0f+expf(-x)); }

__device__ __forceinline__ unsigned short f2bf(float f){
  union { float f; uint32_t u; } v; v.f = f;
  uint32_t r = v.u + 0x7FFFu + ((v.u >> 16) & 1u);
  return (unsigned short)(r >> 16);
}
__device__ __forceinline__ float bf2f(unsigned short s){
  union { uint32_t u; float f; } v; v.u = ((uint32_t)s) << 16;
  return v.f;
}

// ---------------- conversions ----------------
__global__ __launch_bounds__(256) void k_conv_enc(const float* __restrict__ enc, unsigned short* __restrict__ out){
  int i = blockIdx.x*256 + threadIdx.x;   // 6,553,600 threads, 4 elems each
  const float4* e4 = (const float4*)enc;
  float4 v = e4[i];
  ushort4 r;
  r.x = f2bf(v.x); r.y = f2bf(v.y); r.z = f2bf(v.z); r.w = f2bf(v.w);
  ((ushort4*)out)[i] = r;
}

// Bt[n][k] = W[k][n], n<1024 from W1 (We_h), n>=1024 from W2 (Ws_h)
__global__ __launch_bounds__(256) void k_transpose(const float* __restrict__ W1, const float* __restrict__ W2,
                                                   unsigned short* __restrict__ Bt){
  const float* W = blockIdx.z ? W2 : W1;
  int nbase = blockIdx.z * 1024;
  __shared__ float tile[32][33];
  int k0 = blockIdx.y*32, n0 = blockIdx.x*32;
  int tx = threadIdx.x & 31, ty = threadIdx.x >> 5;  // ty 0..7
  for (int i = 0; i < 32; i += 8)
    tile[ty+i][tx] = W[(size_t)(k0+ty+i)*1024 + n0+tx];
  __syncthreads();
  for (int i = 0; i < 32; i += 8)
    Bt[(size_t)(nbase+n0+ty+i)*1024 + k0+tx] = f2bf(tile[tx][ty+i]);
}

// ---------------- small dense chain ----------------
__global__ __launch_bounds__(256) void k_x(const float* __restrict__ x_t, const float* __restrict__ ct_e,
                                           const float* __restrict__ W_xc, const float* __restrict__ b_xc,
                                           float* __restrict__ x){
  int b = blockIdx.x, e = threadIdx.x;
  float acc = b_xc[e];
  for (int k = 0; k < 256;  ++k) acc += x_t[b*256+k]  * W_xc[k*256+e];
  for (int k = 0; k < 1024; ++k) acc += ct_e[b*1024+k]* W_xc[(256+k)*256+e];
  x[b*256+e] = acc;
}

__global__ __launch_bounds__(256) void k_lstm(const float* __restrict__ x, const float* __restrict__ s_h,
                                              const float* __restrict__ s_c,
                                              const float* __restrict__ W_ih, const float* __restrict__ W_hh,
                                              const float* __restrict__ b_ih, const float* __restrict__ b_hh,
                                              float* __restrict__ h_out, float* __restrict__ c_out){
  int b = blockIdx.x;
  int j = threadIdx.x + blockIdx.y*256;   // 0..511
  float gi = b_ih[j]      + b_hh[j];
  float gf = b_ih[512+j]  + b_hh[512+j];
  float gg = b_ih[1024+j] + b_hh[1024+j];
  float go = b_ih[1536+j] + b_hh[1536+j];
  for (int k = 0; k < 256; ++k){
    float xv = x[b*256+k]; const float* w = &W_ih[(size_t)k*2048];
    gi += xv*w[j]; gf += xv*w[512+j]; gg += xv*w[1024+j]; go += xv*w[1536+j];
  }
  for (int k = 0; k < 512; ++k){
    float hv = s_h[b*512+k]; const float* w = &W_hh[(size_t)k*2048];
    gi += hv*w[j]; gf += hv*w[512+j]; gg += hv*w[1024+j]; go += hv*w[1536+j];
  }
  float c = sigf(gf)*s_c[b*512+j] + sigf(gi)*tanhf(gg);
  float h = sigf(go)*tanhf(c);
  h_out[b*512+j] = h;
  c_out[b*512+j] = c;
}

__global__ __launch_bounds__(256) void k_qe(const float* __restrict__ h, const float* __restrict__ c,
                                            const float* __restrict__ We_s, const float* __restrict__ be_s,
                                            float* __restrict__ q_e){
  int b = blockIdx.x;
  int d = threadIdx.x + blockIdx.y*256;   // 0..1023
  float acc = be_s[d];
  for (int k = 0; k < 512; ++k) acc += h[b*512+k]*We_s[(size_t)k*1024 + d];
  for (int k = 0; k < 512; ++k) acc += c[b*512+k]*We_s[(size_t)(512+k)*1024 + d];
  q_e[b*1024+d] = acc;
}

__global__ __launch_bounds__(256) void k_qd(const float* __restrict__ h, const float* __restrict__ Wd_s,
                                            const float* __restrict__ bd_s, float* __restrict__ q_d){
  int b = blockIdx.x;
  int j = threadIdx.x + blockIdx.y*256;   // 0..511
  float acc = bd_s[j];
  for (int k = 0; k < 512; ++k) acc += h[b*512+k]*Wd_s[(size_t)k*512 + j];
  q_d[b*512+j] = acc;
}

// ---------------- the big fused dual-GEMM ----------------
// C[r][n] = sum_k enc_bf[r][k] * W[k][n],  n<1024 -> We_h (et path), n>=1024 -> Ws_h (ets path)
// epilogue: tanh(C + bias) then row-dots (ve / vs1) into et_raw/au_raw, and
// vs2-weighted column sums into et2_acc (ets path only).
__global__ __launch_bounds__(256,2) void k_gemm_big(
    const unsigned short* __restrict__ Abf,   // [25600][1024]
    const unsigned short* __restrict__ Btbf,  // [2048][1024]
    const float* __restrict__ q_e,            // [64][1024]
    const float* __restrict__ bs_h, const float* __restrict__ ve,
    const float* __restrict__ vs1,  const float* __restrict__ vs2,
    float* __restrict__ et_raw, float* __restrict__ au_raw, float* __restrict__ et2_acc)
{
  __shared__ int   rowB_s[128];
  __shared__ float rowW_s[128];
  extern __shared__ __align__(16) char smem[];
  unsigned short (*As)[72] = (unsigned short(*)[72])smem;
  unsigned short (*Bs)[72] = (unsigned short(*)[72])(smem + 128*72*2);
  float (*Cs)[132] = (float(*)[132])smem;

  const int tid = threadIdx.x;
  const int bn = blockIdx.x, bm = blockIdx.y;
  const int r0  = bm*128;
  const int n0g = bn*128;
  const bool etmode = (n0g < 1024);
  const int dbase = etmode ? n0g : (n0g - 1024);

  f32x4 acc[4][4];
  #pragma unroll
  for (int i = 0; i < 4; ++i)
    #pragma unroll
    for (int j = 0; j < 4; ++j){ acc[i][j][0]=0.f; acc[i][j][1]=0.f; acc[i][j][2]=0.f; acc[i][j][3]=0.f; }

  const int wave = tid >> 6, lane = tid & 63;
  const int wm = wave & 1, wn = wave >> 1;
  const int lr = lane & 15, lq = lane >> 4;

  const uint4* Ag = (const uint4*)Abf;   // 8 bf16 per uint4
  const uint4* Bg = (const uint4*)Btbf;

  for (int kt = 0; kt < 16; ++kt){
    __syncthreads();
    #pragma unroll
    for (int q = 0; q < 4; ++q){
      int cidx = q*256 + tid;
      int m = cidx >> 3, ko8 = cidx & 7;
      uint4 va = Ag[(size_t)(r0+m)*128  + kt*8 + ko8];
      *(uint4*)&As[m][ko8*8] = va;
      uint4 vb = Bg[(size_t)(n0g+m)*128 + kt*8 + ko8];
      *(uint4*)&Bs[m][ko8*8] = vb;
    }
    __syncthreads();
    #pragma unroll
    for (int kk = 0; kk < 2; ++kk){
      bf16x8 a[4], b[4];
      #pragma unroll
      for (int i = 0; i < 4; ++i){
        a[i] = *(const bf16x8*)&As[wm*64 + i*16 + lr][kk*32 + lq*8];
        b[i] = *(const bf16x8*)&Bs[wn*64 + i*16 + lr][kk*32 + lq*8];
      }
      #pragma unroll
      for (int mt = 0; mt < 4; ++mt)
        #pragma unroll
        for (int nt = 0; nt < 4; ++nt)
          acc[mt][nt] = __builtin_amdgcn_mfma_f32_16x16x32_bf16(a[mt], b[nt], acc[mt][nt], 0, 0, 0);
    }
  }
  __syncthreads();   // all waves done reading As/Bs before aliasing as Cs

  #pragma unroll
  for (int mt = 0; mt < 4; ++mt)
    #pragma unroll
    for (int nt = 0; nt < 4; ++nt)
      #pragma unroll
      for (int v = 0; v < 4; ++v)
        Cs[wm*64 + mt*16 + lq*4 + v][wn*64 + nt*16 + lr] = acc[mt][nt][v];

  if (tid < 128){
    int r = r0 + tid;
    int b = r / 400;
    rowB_s[tid] = b;
    rowW_s[tid] = vs2[r - b*400];
  }
  __syncthreads();

  // pass1: bias + tanh in place
  for (int i = tid; i < 128*128; i += 256){
    int m = i >> 7, n = i & 127;
    float vb = etmode ? q_e[rowB_s[m]*1024 + dbase + n] : bs_h[dbase + n];
    Cs[m][n] = tanhf(Cs[m][n] + vb);
  }
  __syncthreads();

  // pass2: row dots with ve (et) or vs1 (au)
  {
    int row = tid >> 1, half = tid & 1;
    const float* vv = etmode ? ve : vs1;
    float s = 0.f;
    #pragma unroll 8
    for (int n = half*64; n < half*64 + 64; ++n) s += Cs[row][n] * vv[dbase + n];
    s += __shfl_xor(s, 1);
    if (half == 0){
      float* dst = etmode ? et_raw : au_raw;
      atomicAdd(&dst[r0 + row], s);
    }
  }

  // pass3 (ets only): column sums weighted by vs2[t], split per b
  if (!etmode){
    __syncthreads();
    int col = tid >> 1, rh = tid & 1;
    float a2 = 0.f;
    int curb = rowB_s[rh*64];
    for (int m = rh*64; m < rh*64 + 64; ++m){
      int bb = rowB_s[m];
      if (bb != curb){ atomicAdd(&et2_acc[curb*1024 + dbase + col], a2); a2 = 0.f; curb = bb; }
      a2 += Cs[m][col] * rowW_s[m];
    }
    atomicAdd(&et2_acc[curb*1024 + dbase + col], a2);
  }
}

// ---------------- attention normalizations ----------------
__global__ __launch_bounds__(512) void k_attn_norm(const float* __restrict__ et_raw, const float* __restrict__ au_raw,
                                                   const float* __restrict__ et2_acc,
                                                   const float* __restrict__ sumts, const float* __restrict__ mask,
                                                   float* __restrict__ o_sumn, float* __restrict__ o_au,
                                                   float* __restrict__ o_et2, float* __restrict__ at_ws){
  int b = blockIdx.x, tid = threadIdx.x;
  __shared__ float red[512];
  float w = 0.f;
  if (tid < 400){
    float e  = expf(et_raw[b*400+tid]);
    float st = sumts[b*400+tid];
    o_sumn[b*400+tid] = st + e;
    w = (e/st) * mask[b*400+tid];
  }
  red[tid] = w; __syncthreads();
  for (int s = 256; s > 0; s >>= 1){ if (tid < s) red[tid] += red[tid+s]; __syncthreads(); }
  float invw = 1.0f/red[0];
  __syncthreads();
  if (tid < 400) at_ws[b*400+tid] = w*invw;

  float a = 0.f;
  if (tid < 400) a = sigf(au_raw[b*400+tid]) * mask[b*400+tid];
  red[tid] = a; __syncthreads();
  for (int s = 256; s > 0; s >>= 1){ if (tid < s) red[tid] += red[tid+s]; __syncthreads(); }
  float inva = 1.0f/red[0];
  if (tid < 400) o_au[b*400+tid] = a*inva;

  for (int d = tid; d < 1024; d += 512) o_et2[b*1024+d] = sigf(et2_acc[b*1024+d]);
}

// ct_e_new[b][d] = sum_t at[b][t] * enc[b][t][d]   (bf16 enc copy)
__global__ __launch_bounds__(256) void k_cte(const unsigned short* __restrict__ Abf, const float* __restrict__ at_ws,
                                             float* __restrict__ o_cte){
  int b = blockIdx.y;
  int d = blockIdx.x*256 + threadIdx.x;
  float acc = 0.f;
  for (int t = 0; t < 400; ++t)
    acc += at_ws[b*400+t] * bf2f(Abf[((size_t)(b*400+t))*1024 + d]);
  o_cte[b*1024+d] = acc;
}

// ---------------- intra-decoder attention ----------------
__global__ __launch_bounds__(512) void k_ed(const float* __restrict__ prev_s, const float* __restrict__ Wd_prev,
                                            const float* __restrict__ q_d, const float* __restrict__ vd,
                                            float* __restrict__ tmp_ed){
  int j = threadIdx.x, tau = blockIdx.x, b = blockIdx.y;
  float acc = q_d[b*512+j];
  const float* ps = &prev_s[((size_t)b*50 + tau)*512];
  for (int k = 0; k < 512; ++k) acc += ps[k]*Wd_prev[(size_t)k*512 + j];
  tmp_ed[((size_t)b*50 + tau)*512 + j] = tanhf(acc)*vd[j];
}

__global__ __launch_bounds__(512) void k_ctd(const float* __restrict__ tmp_ed, const float* __restrict__ prev_s,
                                             float* __restrict__ ct_d){
  int b = blockIdx.x, tid = threadIdx.x;
  __shared__ float ed_s[50];
  __shared__ float ad_s[50];
  if (tid < 400){
    int tau = tid >> 3, part = tid & 7;
    const float* tp = &tmp_ed[((size_t)b*50 + tau)*512 + part*64];
    float p = 0.f;
    for (int j = 0; j < 64; ++j) p += tp[j];
    p += __shfl_xor(p, 1); p += __shfl_xor(p, 2); p += __shfl_xor(p, 4);
    if (part == 0) ed_s[tau] = p;
  }
  __syncthreads();
  if (tid == 0){
    float mx = -1e30f;
    for (int t = 0; t < 50; ++t) mx = fmaxf(mx, ed_s[t]);
    float se = 0.f;
    for (int t = 0; t < 50; ++t){ float e = expf(ed_s[t]-mx); ad_s[t] = e; se += e; }
    float inv = 1.f/se;
    for (int t = 0; t < 50; ++t) ad_s[t] *= inv;
  }
  __syncthreads();
  float acc = 0.f;
  for (int t = 0; t < 50; ++t) acc += ad_s[t]*prev_s[((size_t)b*50 + t)*512 + tid];
  ct_d[b*512+tid] = acc;
}

// ---------------- p_gen / out / logits / softmax / scatter ----------------
__global__ __launch_bounds__(256) void k_pgen(const float* __restrict__ cte, const float* __restrict__ ctd,
                                              const float* __restrict__ h, const float* __restrict__ c,
                                              const float* __restrict__ et2,
                                              const float* __restrict__ w_pg_cte, const float* __restrict__ w_pg_ctd,
                                              const float* __restrict__ w_pg_st, const float* __restrict__ w_pg_em,
                                              const float* __restrict__ b_pg_st, float* __restrict__ p_gen){
  int b = blockIdx.x, tid = threadIdx.x;
  float s = 0.f;
  for (int d = tid; d < 1024; d += 256) s += cte[b*1024+d]*w_pg_cte[d] + et2[b*1024+d]*w_pg_em[d];
  for (int d = tid; d < 512;  d += 256) s += ctd[b*512+d]*w_pg_ctd[d] + h[b*512+d]*w_pg_st[d] + c[b*512+d]*w_pg_st[512+d];
  __shared__ float red[256];
  red[tid] = s; __syncthreads();
  for (int k = 128; k > 0; k >>= 1){ if (tid < k) red[tid] += red[tid+k]; __syncthreads(); }
  if (tid == 0) p_gen[b] = sigf(red[0] + b_pg_st[0]);
}

__global__ __launch_bounds__(256) void k_outvec(const float* __restrict__ h, const float* __restrict__ cte,
                                                const float* __restrict__ ctd, const float* __restrict__ et2,
                                                const float* __restrict__ W_V, const float* __restrict__ b_V,
                                                float* __restrict__ out_vec){
  int b = blockIdx.y;
  int j = blockIdx.x*256 + threadIdx.x;   // 0..511
  float acc = b_V[j];
  for (int k = 0; k < 512;  ++k) acc += h[b*512+k]  *W_V[(size_t)k*512 + j];
  for (int k = 0; k < 1024; ++k) acc += cte[b*1024+k]*W_V[(size_t)(512+k)*512 + j];
  for (int k = 0; k < 512;  ++k) acc += ctd[b*512+k]*W_V[(size_t)(1536+k)*512 + j];
  for (int k = 0; k < 1024; ++k) acc += et2[b*1024+k]*W_V[(size_t)(2048+k)*512 + j];
  out_vec[b*512+j] = acc;
}

__global__ __launch_bounds__(256) void k_logits(const float* __restrict__ out_vec, const float* __restrict__ W_V1,
                                                const float* __restrict__ b_V1, float* __restrict__ logits){
  __shared__ float As_[64][68];   // [k][b]
  int tid = threadIdx.x;
  int v = blockIdx.x*256 + tid;
  float acc[64];
  #pragma unroll
  for (int b = 0; b < 64; ++b) acc[b] = 0.f;
  for (int kc = 0; kc < 512; kc += 64){
    __syncthreads();
    for (int i = tid; i < 4096; i += 256){
      int b = i >> 6, kk = i & 63;
      As_[kk][b] = out_vec[b*512 + kc + kk];
    }
    __syncthreads();
    if (v < Vn){
      for (int k = 0; k < 64; ++k){
        float w = W_V1[(size_t)(kc+k)*Vn + v];
        #pragma unroll
        for (int b = 0; b < 64; ++b) acc[b] += As_[k][b]*w;
      }
    }
  }
  if (v < Vn){
    float bb = b_V1[v];
    for (int b = 0; b < 64; ++b) logits[(size_t)b*Vn + v] = acc[b] + bb;
  }
}

__global__ __launch_bounds__(1024) void k_softmax_final(const float* __restrict__ logits, const float* __restrict__ p_gen,
                                                        float* __restrict__ final_out){
  int b = blockIdx.x, tid = threadIdx.x;
  __shared__ float red[1024];
  const float* lrow = &logits[(size_t)b*Vn];
  float mx = -1e30f;
  for (int v = tid; v < Vn; v += 1024) mx = fmaxf(mx, lrow[v]);
  red[tid] = mx; __syncthreads();
  for (int s = 512; s > 0; s >>= 1){ if (tid < s) red[tid] = fmaxf(red[tid], red[tid+s]); __syncthreads(); }
  mx = red[0]; __syncthreads();
  float se = 0.f;
  for (int v = tid; v < Vn; v += 1024) se += expf(lrow[v]-mx);
  red[tid] = se; __syncthreads();
  for (int s = 512; s > 0; s >>= 1){ if (tid < s) red[tid] += red[tid+s]; __syncthreads(); }
  float scale = p_gen[b]/red[0];
  float* frow = &final_out[(size_t)b*VEXTn];
  for (int v = tid; v < Vn; v += 1024) frow[v] = expf(lrow[v]-mx)*scale;
  for (int v = Vn+tid; v < VEXTn; v += 1024) frow[v] = 0.f;
}

__global__ __launch_bounds__(256) void k_scatter(const int* __restrict__ ebev, const float* __restrict__ at_ws,
                                                 const float* __restrict__ p_gen, float* __restrict__ final_out){
  int i = blockIdx.x*256 + threadIdx.x;   // 25600
  int b = i / 400;
  float add = (1.f - p_gen[b]) * at_ws[i];
  atomicAdd(&final_out[(size_t)b*VEXTn + ebev[i]], add);
}

__global__ __launch_bounds__(256) void k_prevs(const float* __restrict__ prev_s, const float* __restrict__ h,
                                               float* __restrict__ o_prevs){
  int i = blockIdx.x*256 + threadIdx.x;   // 64*51*512 = 1,671,168
  int b = i / (51*512);
  int rem = i - b*51*512;
  int tau = rem >> 9, j = rem & 511;
  o_prevs[i] = (tau < 50) ? prev_s[((size_t)b*50 + tau)*512 + j] : h[b*512+j];
}

extern "C" void kernel_launch(void* const* d_in, const int* in_sizes, int n_in,
                              void* d_out, int out_size, void* d_ws, size_t ws_size,
                              hipStream_t stream)
{
  const float* x_t    = (const float*)d_in[0];
  const float* s_h    = (const float*)d_in[1];
  const float* s_c    = (const float*)d_in[2];
  const float* enc    = (const float*)d_in[3];
  const float* mask   = (const float*)d_in[4];
  const float* ct_e   = (const float*)d_in[5];
  const float* sumts  = (const float*)d_in[7];
  const float* prev_s = (const float*)d_in[8];
  const int*   ebev   = (const int*)d_in[9];
  const float* W_xc   = (const float*)d_in[10];
  const float* b_xc   = (const float*)d_in[11];
  const float* W_ih   = (const float*)d_in[12];
  const float* W_hh   = (const float*)d_in[13];
  const float* b_ih   = (const float*)d_in[14];
  const float* b_hh   = (const float*)d_in[15];
  const float* We_h   = (const float*)d_in[16];
  const float* We_s   = (const float*)d_in[17];
  const float* be_s   = (const float*)d_in[18];
  const float* ve     = (const float*)d_in[19];
  const float* Ws_h   = (const float*)d_in[20];
  const float* bs_h   = (const float*)d_in[21];
  const float* vs1    = (const float*)d_in[22];
  const float* vs2    = (const float*)d_in[23];
  const float* Wd_prev= (const float*)d_in[24];
  const float* Wd_s   = (const float*)d_in[25];
  const float* bd_s   = (const float*)d_in[26];
  const float* vd     = (const float*)d_in[27];
  const float* w_pg_em  = (const float*)d_in[28];
  const float* w_pg_cte = (const float*)d_in[29];
  const float* w_pg_ctd = (const float*)d_in[30];
  const float* w_pg_st  = (const float*)d_in[31];
  const float* b_pg_st  = (const float*)d_in[32];
  const float* W_V    = (const float*)d_in[33];
  const float* b_V    = (const float*)d_in[34];
  const float* W_V1   = (const float*)d_in[35];
  const float* b_V1   = (const float*)d_in[36];
  (void)in_sizes; (void)n_in; (void)out_size; (void)ws_size;

  float* out = (float*)d_out;
  float* o_final = out;                 // 64*50100 = 3,206,400
  float* o_h     = out + 3206400;       // 32768
  float* o_c     = out + 3239168;       // 32768
  float* o_cte   = out + 3271936;       // 65536
  float* o_au    = out + 3337472;       // 25600
  float* o_et2   = out + 3363072;       // 65536
  float* o_sumn  = out + 3428608;       // 25600
  float* o_prevs = out + 3454208;       // 1,671,168

  char* ws = (char*)d_ws;
  float* et_raw  = (float*)(ws + 0);          // 25600 f (zeroed)
  float* au_raw  = (float*)(ws + 102400);     // 25600 f (zeroed)
  float* et2_acc = (float*)(ws + 204800);     // 65536 f (zeroed)
  float* at_ws   = (float*)(ws + 466944);     // 25600 f
  float* x_ws    = (float*)(ws + 569344);     // 16384 f
  float* q_e     = (float*)(ws + 634880);     // 65536 f
  float* q_d     = (float*)(ws + 897024);     // 32768 f
  float* ct_d    = (float*)(ws + 1028096);    // 32768 f
  float* p_gen   = (float*)(ws + 1159168);    // 64 f
  float* out_vec = (float*)(ws + 1159424);    // 32768 f
  float* tmp_ed  = (float*)(ws + 1290496);    // 1,638,400 f
  float* logits  = (float*)(ws + 7844096);    // 3,200,000 f
  unsigned short* enc_bf = (unsigned short*)(ws + 20644096);  // 26,214,400 bf16
  unsigned short* Bt_bf  = (unsigned short*)(ws + 73072896);  // 2048*1024 bf16

  hipMemsetAsync(ws, 0, 466944, stream);
  k_conv_enc<<<25600, 256, 0, stream>>>(enc, enc_bf);
  k_transpose<<<dim3(32,32,2), 256, 0, stream>>>(We_h, Ws_h, Bt_bf);
  k_x<<<64, 256, 0, stream>>>(x_t, ct_e, W_xc, b_xc, x_ws);
  k_lstm<<<dim3(64,2), 256, 0, stream>>>(x_ws, s_h, s_c, W_ih, W_hh, b_ih, b_hh, o_h, o_c);
  k_qe<<<dim3(64,4), 256, 0, stream>>>(o_h, o_c, We_s, be_s, q_e);
  k_qd<<<dim3(64,2), 256, 0, stream>>>(o_h, Wd_s, bd_s, q_d);
  k_gemm_big<<<dim3(16,200), 256, 67584, stream>>>(enc_bf, Bt_bf, q_e, bs_h, ve, vs1, vs2,
                                                   et_raw, au_raw, et2_acc);
  k_attn_norm<<<64, 512, 0, stream>>>(et_raw, au_raw, et2_acc, sumts, mask, o_sumn, o_au, o_et2, at_ws);
  k_cte<<<dim3(4,64), 256, 0, stream>>>(enc_bf, at_ws, o_cte);
  k_ed<<<dim3(50,64), 512, 0, stream>>>(prev_s, Wd_prev, q_d, vd, tmp_ed);
  k_ctd<<<64, 512, 0, stream>>>(tmp_ed, prev_s, ct_d);
  k_pgen<<<64, 256, 0, stream>>>(o_cte, ct_d, o_h, o_c, o_et2, w_pg_cte, w_pg_ctd, w_pg_st, w_pg_em, b_pg_st, p_gen);
  k_outvec<<<dim3(2,64), 256, 0, stream>>>(o_h, o_cte, ct_d, o_et2, W_V, b_V, out_vec);
  k_logits<<<196, 256, 0, stream>>>(out_vec, W_V1, b_V1, logits);
  k_softmax_final<<<64, 1024, 0, stream>>>(logits, p_gen, o_final);
  k_scatter<<<100, 256, 0, stream>>>(ebev, at_ws, p_gen, o_final);
  k_prevs<<<6528, 256, 0, stream>>>(prev_s, o_h, o_prevs);
}

// Round 2
// 1344.990 us; speedup vs baseline: 1.3130x; 1.3130x over previous
//
#include <hip/hip_runtime.h>
#include <stdint.h>

#define Bn 64
#define Tn 400
#define Hn 512
#define En 256
#define Vn 50000
#define NOOVn 100
#define TPn 50
#define H2n 1024
#define VEXTn (Vn+NOOVn)  // 50100

typedef __bf16 bf16x8 __attribute__((ext_vector_type(8)));
typedef float  f32x4  __attribute__((ext_vector_type(4)));

__device__ __forceinline__ float sigf(float x){ return 1.0f/(1.0f+__expf(-x)); }
__device__ __forceinline__ float tanh_fast(float x){
  float e = __expf(2.0f*x);
  return (e-1.0f)/(e+1.0f);
}

__device__ __forceinline__ unsigned short f2bf(float f){
  union { float f; uint32_t u; } v; v.f = f;
  uint32_t r = v.u + 0x7FFFu + ((v.u >> 16) & 1u);
  return (unsigned short)(r >> 16);
}
__device__ __forceinline__ float bf2f(unsigned short s){
  union { uint32_t u; float f; } v; v.u = ((uint32_t)s) << 16;
  return v.f;
}

__device__ __forceinline__ void async16(const void* g, void* l){
  __builtin_amdgcn_global_load_lds((__attribute__((address_space(1))) void*)g,
                                   (__attribute__((address_space(3))) void*)l, 16, 0, 0);
}

// ---------------- conversions ----------------
__global__ __launch_bounds__(256) void k_conv_enc(const float* __restrict__ enc, unsigned short* __restrict__ out){
  int i = blockIdx.x*256 + threadIdx.x;
  const float4* e4 = (const float4*)enc;
  float4 v = e4[i];
  ushort4 r;
  r.x = f2bf(v.x); r.y = f2bf(v.y); r.z = f2bf(v.z); r.w = f2bf(v.w);
  ((ushort4*)out)[i] = r;
}

// Bt[n][k] = W[k][n], n<1024 from W1 (We_h), n>=1024 from W2 (Ws_h)
__global__ __launch_bounds__(256) void k_transpose(const float* __restrict__ W1, const float* __restrict__ W2,
                                                   unsigned short* __restrict__ Bt){
  const float* W = blockIdx.z ? W2 : W1;
  int nbase = blockIdx.z * 1024;
  __shared__ float tile[32][33];
  int k0 = blockIdx.y*32, n0 = blockIdx.x*32;
  int tx = threadIdx.x & 31, ty = threadIdx.x >> 5;  // ty 0..7
  for (int i = 0; i < 32; i += 8)
    tile[ty+i][tx] = W[(size_t)(k0+ty+i)*1024 + n0+tx];
  __syncthreads();
  for (int i = 0; i < 32; i += 8)
    Bt[(size_t)(nbase+n0+ty+i)*1024 + k0+tx] = f2bf(tile[tx][ty+i]);
}

// ---------------- small dense chain ----------------
__global__ __launch_bounds__(256) void k_x(const float* __restrict__ x_t, const float* __restrict__ ct_e,
                                           const float* __restrict__ W_xc, const float* __restrict__ b_xc,
                                           float* __restrict__ x){
  int b = blockIdx.x, e = threadIdx.x;
  float acc = b_xc[e];
  for (int k = 0; k < 256;  ++k) acc += x_t[b*256+k]  * W_xc[k*256+e];
  for (int k = 0; k < 1024; ++k) acc += ct_e[b*1024+k]* W_xc[(256+k)*256+e];
  x[b*256+e] = acc;
}

__global__ __launch_bounds__(256) void k_lstm(const float* __restrict__ x, const float* __restrict__ s_h,
                                              const float* __restrict__ s_c,
                                              const float* __restrict__ W_ih, const float* __restrict__ W_hh,
                                              const float* __restrict__ b_ih, const float* __restrict__ b_hh,
                                              float* __restrict__ h_out, float* __restrict__ c_out){
  int b = blockIdx.x;
  int j = threadIdx.x + blockIdx.y*256;   // 0..511
  float gi = b_ih[j]      + b_hh[j];
  float gf = b_ih[512+j]  + b_hh[512+j];
  float gg = b_ih[1024+j] + b_hh[1024+j];
  float go = b_ih[1536+j] + b_hh[1536+j];
  for (int k = 0; k < 256; ++k){
    float xv = x[b*256+k]; const float* w = &W_ih[(size_t)k*2048];
    gi += xv*w[j]; gf += xv*w[512+j]; gg += xv*w[1024+j]; go += xv*w[1536+j];
  }
  for (int k = 0; k < 512; ++k){
    float hv = s_h[b*512+k]; const float* w = &W_hh[(size_t)k*2048];
    gi += hv*w[j]; gf += hv*w[512+j]; gg += hv*w[1024+j]; go += hv*w[1536+j];
  }
  float c = sigf(gf)*s_c[b*512+j] + sigf(gi)*tanh_fast(gg);
  float h = sigf(go)*tanh_fast(c);
  h_out[b*512+j] = h;
  c_out[b*512+j] = c;
}

__global__ __launch_bounds__(256) void k_qe(const float* __restrict__ h, const float* __restrict__ c,
                                            const float* __restrict__ We_s, const float* __restrict__ be_s,
                                            float* __restrict__ q_e){
  int b = blockIdx.x;
  int d = threadIdx.x + blockIdx.y*256;   // 0..1023
  float acc = be_s[d];
  for (int k = 0; k < 512; ++k) acc += h[b*512+k]*We_s[(size_t)k*1024 + d];
  for (int k = 0; k < 512; ++k) acc += c[b*512+k]*We_s[(size_t)(512+k)*1024 + d];
  q_e[b*1024+d] = acc;
}

__global__ __launch_bounds__(256) void k_qd(const float* __restrict__ h, const float* __restrict__ Wd_s,
                                            const float* __restrict__ bd_s, float* __restrict__ q_d){
  int b = blockIdx.x;
  int j = threadIdx.x + blockIdx.y*256;   // 0..511
  float acc = bd_s[j];
  for (int k = 0; k < 512; ++k) acc += h[b*512+k]*Wd_s[(size_t)k*512 + j];
  q_d[b*512+j] = acc;
}

// ---------------- the big fused dual-GEMM (m97 pattern) ----------------
// C[r][n] = sum_k enc_bf[r][k] * W[k][n],  n<1024 -> We_h (et path), n>=1024 -> Ws_h (ets path)
// Epilogue entirely in registers: tanh(C+bias), row dots with ve/vs1 -> et_raw/au_raw,
// vs2-weighted column sums (split per batch b) -> et2_acc.
__global__ __launch_bounds__(256,3) void k_gemm_big(
    const unsigned short* __restrict__ Abf,   // [25600][1024]
    const unsigned short* __restrict__ Btbf,  // [2048][1024]
    const float* __restrict__ q_e,            // [64][1024]
    const float* __restrict__ bs_h, const float* __restrict__ ve,
    const float* __restrict__ vs1,  const float* __restrict__ vs2,
    float* __restrict__ et_raw, float* __restrict__ au_raw, float* __restrict__ et2_acc)
{
  __shared__ __align__(16) unsigned short As[128*64];
  __shared__ __align__(16) unsigned short Bs[128*64];
  __shared__ float bias2_s[2][128];
  __shared__ float vv_s[128];
  __shared__ float rowW_s[128];
  __shared__ unsigned char rowSel_s[128];

  const int tid = threadIdx.x;
  const int bn = blockIdx.x, bm = blockIdx.y;
  const int r0  = bm*128;
  const int n0g = bn*128;
  const bool etmode = (n0g < 1024);
  const int dbase = etmode ? n0g : (n0g - 1024);
  const int b_lo = r0/400;
  const int b_hi = min(b_lo+1, 63);
  const bool bcross = (r0/400) != ((r0+127)/400);

  if (tid < 128){
    int r = r0 + tid;
    int bb = r/400;
    rowSel_s[tid] = (unsigned char)(bb - b_lo);
    rowW_s[tid]   = vs2[r - bb*400];
    vv_s[tid]     = etmode ? ve[dbase+tid] : vs1[dbase+tid];
    bias2_s[0][tid] = etmode ? q_e[b_lo*1024 + dbase + tid] : bs_h[dbase+tid];
    bias2_s[1][tid] = etmode ? q_e[b_hi*1024 + dbase + tid] : bs_h[dbase+tid];
  }

  const int w = tid >> 6, lane = tid & 63;
  const int wm = w & 1, wn = w >> 1;
  const int lr = lane & 15, lq = lane >> 4;

  // staging: wave w, instr q -> rows w*32+q*8 .. +7; lane l -> row +(l>>3), col (l&7)*8
  const int srow = lane >> 3, scol = (lane & 7)*8;
  const unsigned short* gA0 = Abf  + (size_t)(r0  + w*32 + srow)*1024 + scol;
  const unsigned short* gB0 = Btbf + (size_t)(n0g + w*32 + srow)*1024 + scol;
  unsigned short* lA0 = As + w*32*64;
  unsigned short* lB0 = Bs + w*32*64;

  f32x4 acc[4][4];
  #pragma unroll
  for (int i = 0; i < 4; ++i)
    #pragma unroll
    for (int j = 0; j < 4; ++j){ acc[i][j][0]=0.f; acc[i][j][1]=0.f; acc[i][j][2]=0.f; acc[i][j][3]=0.f; }

  for (int kt = 0; kt < 16; ++kt){
    __syncthreads();
    #pragma unroll
    for (int q = 0; q < 4; ++q){
      async16(gA0 + (size_t)q*8*1024 + kt*64, lA0 + q*512);
      async16(gB0 + (size_t)q*8*1024 + kt*64, lB0 + q*512);
    }
    __syncthreads();   // drains vmcnt -> tiles visible
    #pragma unroll
    for (int kk = 0; kk < 2; ++kk){
      bf16x8 a[4], b[4];
      #pragma unroll
      for (int i = 0; i < 4; ++i){
        a[i] = *(const bf16x8*)&As[(wm*64 + i*16 + lr)*64 + kk*32 + lq*8];
        b[i] = *(const bf16x8*)&Bs[(wn*64 + i*16 + lr)*64 + kk*32 + lq*8];
      }
      #pragma unroll
      for (int mt = 0; mt < 4; ++mt)
        #pragma unroll
        for (int nt = 0; nt < 4; ++nt)
          acc[mt][nt] = __builtin_amdgcn_mfma_f32_16x16x32_bf16(a[mt], b[nt], acc[mt][nt], 0, 0, 0);
    }
  }

  // ---- register epilogue ----
  float vvr[4], bias0[4], bias1[4];
  #pragma unroll
  for (int nt = 0; nt < 4; ++nt){
    int n = wn*64 + nt*16 + lr;
    vvr[nt]   = vv_s[n];
    bias0[nt] = bias2_s[0][n];
    bias1[nt] = bias2_s[1][n];
  }

  float rowdot[16];
  float colacc[4][2];
  #pragma unroll
  for (int nt = 0; nt < 4; ++nt){ colacc[nt][0]=0.f; colacc[nt][1]=0.f; }

  #pragma unroll
  for (int mt = 0; mt < 4; ++mt){
    #pragma unroll
    for (int v = 0; v < 4; ++v){
      int m = wm*64 + mt*16 + lq*4 + v;
      int sel = rowSel_s[m];
      float rw = rowW_s[m];
      float rd = 0.f;
      #pragma unroll
      for (int nt = 0; nt < 4; ++nt){
        float t = tanh_fast(acc[mt][nt][v] + (sel ? bias1[nt] : bias0[nt]));
        rd += t * vvr[nt];
        if (!etmode) colacc[nt][sel] += t * rw;
      }
      rowdot[mt*4+v] = rd;
    }
  }

  // reduce row dots over lr (16 lanes) -> atomic per row
  #pragma unroll
  for (int i = 0; i < 16; ++i){
    float s = rowdot[i];
    s += __shfl_xor(s,1); s += __shfl_xor(s,2); s += __shfl_xor(s,4); s += __shfl_xor(s,8);
    rowdot[i] = s;
  }
  if (lr == 0){
    float* dst = etmode ? et_raw : au_raw;
    #pragma unroll
    for (int i = 0; i < 16; ++i){
      int m = wm*64 + (i>>2)*16 + lq*4 + (i&3);
      atomicAdd(&dst[r0+m], rowdot[i]);
    }
  }

  // reduce column sums over lq (4 lanes) -> atomic per column per batch segment
  if (!etmode){
    #pragma unroll
    for (int nt = 0; nt < 4; ++nt){
      #pragma unroll
      for (int s = 0; s < 2; ++s){
        float c = colacc[nt][s];
        c += __shfl_xor(c,16); c += __shfl_xor(c,32);
        if (lq == 0 && (s == 0 || bcross)){
          int n = wn*64 + nt*16 + lr;
          atomicAdd(&et2_acc[(b_lo+s)*1024 + dbase + n], c);
        }
      }
    }
  }
}

// ---------------- attention normalizations ----------------
__global__ __launch_bounds__(512) void k_attn_norm(const float* __restrict__ et_raw, const float* __restrict__ au_raw,
                                                   const float* __restrict__ et2_acc,
                                                   const float* __restrict__ sumts, const float* __restrict__ mask,
                                                   float* __restrict__ o_sumn, float* __restrict__ o_au,
                                                   float* __restrict__ o_et2, float* __restrict__ at_ws){
  int b = blockIdx.x, tid = threadIdx.x;
  __shared__ float red[512];
  float w = 0.f;
  if (tid < 400){
    float e  = __expf(et_raw[b*400+tid]);
    float st = sumts[b*400+tid];
    o_sumn[b*400+tid] = st + e;
    w = (e/st) * mask[b*400+tid];
  }
  red[tid] = w; __syncthreads();
  for (int s = 256; s > 0; s >>= 1){ if (tid < s) red[tid] += red[tid+s]; __syncthreads(); }
  float invw = 1.0f/red[0];
  __syncthreads();
  if (tid < 400) at_ws[b*400+tid] = w*invw;

  float a = 0.f;
  if (tid < 400) a = sigf(au_raw[b*400+tid]) * mask[b*400+tid];
  red[tid] = a; __syncthreads();
  for (int s = 256; s > 0; s >>= 1){ if (tid < s) red[tid] += red[tid+s]; __syncthreads(); }
  float inva = 1.0f/red[0];
  if (tid < 400) o_au[b*400+tid] = a*inva;

  for (int d = tid; d < 1024; d += 512) o_et2[b*1024+d] = sigf(et2_acc[b*1024+d]);
}

// ct_e_new[b][d] = sum_t at[b][t] * enc[b][t][d]   (bf16 enc copy)
__global__ __launch_bounds__(256) void k_cte(const unsigned short* __restrict__ Abf, const float* __restrict__ at_ws,
                                             float* __restrict__ o_cte){
  int b = blockIdx.y;
  int d = blockIdx.x*256 + threadIdx.x;
  float acc = 0.f;
  for (int t = 0; t < 400; ++t)
    acc += at_ws[b*400+t] * bf2f(Abf[((size_t)(b*400+t))*1024 + d]);
  o_cte[b*1024+d] = acc;
}

// ---------------- intra-decoder attention ----------------
// grid (4,64): bx&1 -> j half, bx>>1 -> tau half. prev_s reads are wave-uniform (scalar loads).
__global__ __launch_bounds__(256) void k_ed(const float* __restrict__ prev_s, const float* __restrict__ Wd_prev,
                                            const float* __restrict__ q_d, const float* __restrict__ vd,
                                            float* __restrict__ tmp_ed){
  int b = blockIdx.y;
  int j = (blockIdx.x & 1)*256 + threadIdx.x;
  int taub = (blockIdx.x >> 1)*25;
  float acc[25];
  #pragma unroll
  for (int t = 0; t < 25; ++t) acc[t] = 0.f;
  const float* ps = &prev_s[((size_t)b*50 + taub)*512];
  for (int k = 0; k < 512; ++k){
    float wv = Wd_prev[(size_t)k*512 + j];
    #pragma unroll
    for (int t = 0; t < 25; ++t) acc[t] += ps[(size_t)t*512 + k] * wv;
  }
  float qv = q_d[b*512+j], vdj = vd[j];
  #pragma unroll
  for (int t = 0; t < 25; ++t)
    tmp_ed[((size_t)b*50 + taub + t)*512 + j] = tanh_fast(acc[t] + qv) * vdj;
}

__global__ __launch_bounds__(512) void k_ctd(const float* __restrict__ tmp_ed, const float* __restrict__ prev_s,
                                             float* __restrict__ ct_d){
  int b = blockIdx.x, tid = threadIdx.x;
  __shared__ float ed_s[50];
  __shared__ float ad_s[50];
  if (tid < 400){
    int tau = tid >> 3, part = tid & 7;
    const float* tp = &tmp_ed[((size_t)b*50 + tau)*512 + part*64];
    float p = 0.f;
    for (int j = 0; j < 64; ++j) p += tp[j];
    p += __shfl_xor(p, 1); p += __shfl_xor(p, 2); p += __shfl_xor(p, 4);
    if (part == 0) ed_s[tau] = p;
  }
  __syncthreads();
  if (tid == 0){
    float mx = -1e30f;
    for (int t = 0; t < 50; ++t) mx = fmaxf(mx, ed_s[t]);
    float se = 0.f;
    for (int t = 0; t < 50; ++t){ float e = __expf(ed_s[t]-mx); ad_s[t] = e; se += e; }
    float inv = 1.f/se;
    for (int t = 0; t < 50; ++t) ad_s[t] *= inv;
  }
  __syncthreads();
  float acc = 0.f;
  for (int t = 0; t < 50; ++t) acc += ad_s[t]*prev_s[((size_t)b*50 + t)*512 + tid];
  ct_d[b*512+tid] = acc;
}

// ---------------- p_gen / out / logits / softmax / scatter ----------------
__global__ __launch_bounds__(256) void k_pgen(const float* __restrict__ cte, const float* __restrict__ ctd,
                                              const float* __restrict__ h, const float* __restrict__ c,
                                              const float* __restrict__ et2,
                                              const float* __restrict__ w_pg_cte, const float* __restrict__ w_pg_ctd,
                                              const float* __restrict__ w_pg_st, const float* __restrict__ w_pg_em,
                                              const float* __restrict__ b_pg_st, float* __restrict__ p_gen){
  int b = blockIdx.x, tid = threadIdx.x;
  float s = 0.f;
  for (int d = tid; d < 1024; d += 256) s += cte[b*1024+d]*w_pg_cte[d] + et2[b*1024+d]*w_pg_em[d];
  for (int d = tid; d < 512;  d += 256) s += ctd[b*512+d]*w_pg_ctd[d] + h[b*512+d]*w_pg_st[d] + c[b*512+d]*w_pg_st[512+d];
  __shared__ float red[256];
  red[tid] = s; __syncthreads();
  for (int k = 128; k > 0; k >>= 1){ if (tid < k) red[tid] += red[tid+k]; __syncthreads(); }
  if (tid == 0) p_gen[b] = sigf(red[0] + b_pg_st[0]);
}

__global__ __launch_bounds__(256) void k_outvec(const float* __restrict__ h, const float* __restrict__ cte,
                                                const float* __restrict__ ctd, const float* __restrict__ et2,
                                                const float* __restrict__ W_V, const float* __restrict__ b_V,
                                                float* __restrict__ out_vec){
  int b = blockIdx.y;
  int j = blockIdx.x*256 + threadIdx.x;   // 0..511
  float acc = b_V[j];
  for (int k = 0; k < 512;  ++k) acc += h[b*512+k]  *W_V[(size_t)k*512 + j];
  for (int k = 0; k < 1024; ++k) acc += cte[b*1024+k]*W_V[(size_t)(512+k)*512 + j];
  for (int k = 0; k < 512;  ++k) acc += ctd[b*512+k]*W_V[(size_t)(1536+k)*512 + j];
  for (int k = 0; k < 1024; ++k) acc += et2[b*1024+k]*W_V[(size_t)(2048+k)*512 + j];
  out_vec[b*512+j] = acc;
}

// out_vec reads are wave-uniform -> scalar loads; W_V1 reads coalesced per lane.
__global__ __launch_bounds__(256) void k_logits(const float* __restrict__ out_vec, const float* __restrict__ W_V1,
                                                const float* __restrict__ b_V1, float* __restrict__ logits){
  int tid = threadIdx.x;
  int v = blockIdx.x*256 + tid;
  int vc = (v < Vn) ? v : (Vn-1);
  const float* wp = W_V1 + vc;
  float acc[64];
  #pragma unroll
  for (int b = 0; b < 64; ++b) acc[b] = 0.f;
  for (int k = 0; k < 512; ++k){
    float w = wp[(size_t)k*Vn];
    #pragma unroll
    for (int b = 0; b < 64; ++b) acc[b] += out_vec[b*512+k]*w;
  }
  if (v < Vn){
    float bb = b_V1[v];
    for (int b = 0; b < 64; ++b) logits[(size_t)b*Vn + v] = acc[b] + bb;
  }
}

__global__ __launch_bounds__(1024) void k_softmax_final(const float* __restrict__ logits, const float* __restrict__ p_gen,
                                                        float* __restrict__ final_out){
  int b = blockIdx.x, tid = threadIdx.x;
  __shared__ float red[1024];
  const float* lrow = &logits[(size_t)b*Vn];
  float mx = -1e30f;
  for (int v = tid; v < Vn; v += 1024) mx = fmaxf(mx, lrow[v]);
  red[tid] = mx; __syncthreads();
  for (int s = 512; s > 0; s >>= 1){ if (tid < s) red[tid] = fmaxf(red[tid], red[tid+s]); __syncthreads(); }
  mx = red[0]; __syncthreads();
  float se = 0.f;
  for (int v = tid; v < Vn; v += 1024) se += __expf(lrow[v]-mx);
  red[tid] = se; __syncthreads();
  for (int s = 512; s > 0; s >>= 1){ if (tid < s) red[tid] += red[tid+s]; __syncthreads(); }
  float scale = p_gen[b]/red[0];
  float* frow = &final_out[(size_t)b*VEXTn];
  for (int v = tid; v < Vn; v += 1024) frow[v] = __expf(lrow[v]-mx)*scale;
  for (int v = Vn+tid; v < VEXTn; v += 1024) frow[v] = 0.f;
}

__global__ __launch_bounds__(256) void k_scatter(const int* __restrict__ ebev, const float* __restrict__ at_ws,
                                                 const float* __restrict__ p_gen, float* __restrict__ final_out){
  int i = blockIdx.x*256 + threadIdx.x;   // 25600
  int b = i / 400;
  float add = (1.f - p_gen[b]) * at_ws[i];
  atomicAdd(&final_out[(size_t)b*VEXTn + ebev[i]], add);
}

__global__ __launch_bounds__(256) void k_prevs(const float* __restrict__ prev_s, const float* __restrict__ h,
                                               float* __restrict__ o_prevs){
  int i = blockIdx.x*256 + threadIdx.x;   // 64*51*512 = 1,671,168
  int b = i / (51*512);
  int rem = i - b*51*512;
  int tau = rem >> 9, j = rem & 511;
  o_prevs[i] = (tau < 50) ? prev_s[((size_t)b*50 + tau)*512 + j] : h[b*512+j];
}

extern "C" void kernel_launch(void* const* d_in, const int* in_sizes, int n_in,
                              void* d_out, int out_size, void* d_ws, size_t ws_size,
                              hipStream_t stream)
{
  const float* x_t    = (const float*)d_in[0];
  const float* s_h    = (const float*)d_in[1];
  const float* s_c    = (const float*)d_in[2];
  const float* enc    = (const float*)d_in[3];
  const float* mask   = (const float*)d_in[4];
  const float* ct_e   = (const float*)d_in[5];
  const float* sumts  = (const float*)d_in[7];
  const float* prev_s = (const float*)d_in[8];
  const int*   ebev   = (const int*)d_in[9];
  const float* W_xc   = (const float*)d_in[10];
  const float* b_xc   = (const float*)d_in[11];
  const float* W_ih   = (const float*)d_in[12];
  const float* W_hh   = (const float*)d_in[13];
  const float* b_ih   = (const float*)d_in[14];
  const float* b_hh   = (const float*)d_in[15];
  const float* We_h   = (const float*)d_in[16];
  const float* We_s   = (const float*)d_in[17];
  const float* be_s   = (const float*)d_in[18];
  const float* ve     = (const float*)d_in[19];
  const float* Ws_h   = (const float*)d_in[20];
  const float* bs_h   = (const float*)d_in[21];
  const float* vs1    = (const float*)d_in[22];
  const float* vs2    = (const float*)d_in[23];
  const float* Wd_prev= (const float*)d_in[24];
  const float* Wd_s   = (const float*)d_in[25];
  const float* bd_s   = (const float*)d_in[26];
  const float* vd     = (const float*)d_in[27];
  const float* w_pg_em  = (const float*)d_in[28];
  const float* w_pg_cte = (const float*)d_in[29];
  const float* w_pg_ctd = (const float*)d_in[30];
  const float* w_pg_st  = (const float*)d_in[31];
  const float* b_pg_st  = (const float*)d_in[32];
  const float* W_V    = (const float*)d_in[33];
  const float* b_V    = (const float*)d_in[34];
  const float* W_V1   = (const float*)d_in[35];
  const float* b_V1   = (const float*)d_in[36];
  (void)in_sizes; (void)n_in; (void)out_size; (void)ws_size;

  float* out = (float*)d_out;
  float* o_final = out;                 // 64*50100 = 3,206,400
  float* o_h     = out + 3206400;       // 32768
  float* o_c     = out + 3239168;       // 32768
  float* o_cte   = out + 3271936;       // 65536
  float* o_au    = out + 3337472;       // 25600
  float* o_et2   = out + 3363072;       // 65536
  float* o_sumn  = out + 3428608;       // 25600
  float* o_prevs = out + 3454208;       // 1,671,168

  char* ws = (char*)d_ws;
  float* et_raw  = (float*)(ws + 0);          // 25600 f (zeroed)
  float* au_raw  = (float*)(ws + 102400);     // 25600 f (zeroed)
  float* et2_acc = (float*)(ws + 204800);     // 65536 f (zeroed)
  float* at_ws   = (float*)(ws + 466944);     // 25600 f
  float* x_ws    = (float*)(ws + 569344);     // 16384 f
  float* q_e     = (float*)(ws + 634880);     // 65536 f
  float* q_d     = (float*)(ws + 897024);     // 32768 f
  float* ct_d    = (float*)(ws + 1028096);    // 32768 f
  float* p_gen   = (float*)(ws + 1159168);    // 64 f
  float* out_vec = (float*)(ws + 1159424);    // 32768 f
  float* tmp_ed  = (float*)(ws + 1290496);    // 1,638,400 f
  float* logits  = (float*)(ws + 7844096);    // 3,200,000 f
  unsigned short* enc_bf = (unsigned short*)(ws + 20644096);  // 26,214,400 bf16
  unsigned short* Bt_bf  = (unsigned short*)(ws + 73072896);  // 2048*1024 bf16

  hipMemsetAsync(ws, 0, 466944, stream);
  k_conv_enc<<<25600, 256, 0, stream>>>(enc, enc_bf);
  k_transpose<<<dim3(32,32,2), 256, 0, stream>>>(We_h, Ws_h, Bt_bf);
  k_x<<<64, 256, 0, stream>>>(x_t, ct_e, W_xc, b_xc, x_ws);
  k_lstm<<<dim3(64,2), 256, 0, stream>>>(x_ws, s_h, s_c, W_ih, W_hh, b_ih, b_hh, o_h, o_c);
  k_qe<<<dim3(64,4), 256, 0, stream>>>(o_h, o_c, We_s, be_s, q_e);
  k_qd<<<dim3(64,2), 256, 0, stream>>>(o_h, Wd_s, bd_s, q_d);
  k_gemm_big<<<dim3(16,200), 256, 0, stream>>>(enc_bf, Bt_bf, q_e, bs_h, ve, vs1, vs2,
                                               et_raw, au_raw, et2_acc);
  k_attn_norm<<<64, 512, 0, stream>>>(et_raw, au_raw, et2_acc, sumts, mask, o_sumn, o_au, o_et2, at_ws);
  k_cte<<<dim3(4,64), 256, 0, stream>>>(enc_bf, at_ws, o_cte);
  k_ed<<<dim3(4,64), 256, 0, stream>>>(prev_s, Wd_prev, q_d, vd, tmp_ed);
  k_ctd<<<64, 512, 0, stream>>>(tmp_ed, prev_s, ct_d);
  k_pgen<<<64, 256, 0, stream>>>(o_cte, ct_d, o_h, o_c, o_et2, w_pg_cte, w_pg_ctd, w_pg_st, w_pg_em, b_pg_st, p_gen);
  k_outvec<<<dim3(2,64), 256, 0, stream>>>(o_h, o_cte, ct_d, o_et2, W_V, b_V, out_vec);
  k_logits<<<196, 256, 0, stream>>>(out_vec, W_V1, b_V1, logits);
  k_softmax_final<<<64, 1024, 0, stream>>>(logits, p_gen, o_final);
  k_scatter<<<100, 256, 0, stream>>>(ebev, at_ws, p_gen, o_final);
  k_prevs<<<6528, 256, 0, stream>>>(prev_s, o_h, o_prevs);
}

// Round 3
// 1141.928 us; speedup vs baseline: 1.5464x; 1.1778x over previous
//
#include <hip/hip_runtime.h>
#include <stdint.h>

#define Bn 64
#define Tn 400
#define Hn 512
#define En 256
#define Vn 50000
#define NOOVn 100
#define TPn 50
#define H2n 1024
#define VEXTn (Vn+NOOVn)  // 50100
#define VPADn 50048       // 782*64

typedef __bf16 bf16x8 __attribute__((ext_vector_type(8)));
typedef float  f32x4  __attribute__((ext_vector_type(4)));

__device__ __forceinline__ float sigf(float x){ return 1.0f/(1.0f+__expf(-x)); }
__device__ __forceinline__ float tanh_fast(float x){
  float e = __expf(2.0f*x);
  return (e-1.0f)/(e+1.0f);
}

__device__ __forceinline__ unsigned short f2bf(float f){
  union { float f; uint32_t u; } v; v.f = f;
  uint32_t r = v.u + 0x7FFFu + ((v.u >> 16) & 1u);
  return (unsigned short)(r >> 16);
}
__device__ __forceinline__ float bf2f(unsigned short s){
  union { uint32_t u; float f; } v; v.u = ((uint32_t)s) << 16;
  return v.f;
}

__device__ __forceinline__ void async16(const void* g, void* l){
  __builtin_amdgcn_global_load_lds((__attribute__((address_space(1))) void*)g,
                                   (__attribute__((address_space(3))) void*)l, 16, 0, 0);
}

// ---------------- conversions ----------------
__global__ __launch_bounds__(256) void k_conv_enc(const float* __restrict__ enc, unsigned short* __restrict__ out){
  int i = blockIdx.x*256 + threadIdx.x;
  const float4* e4 = (const float4*)enc;
  float4 v = e4[i];
  ushort4 r;
  r.x = f2bf(v.x); r.y = f2bf(v.y); r.z = f2bf(v.z); r.w = f2bf(v.w);
  ((ushort4*)out)[i] = r;
}

// Bt[n][k] = W[k][n], n<1024 from W1 (We_h), n>=1024 from W2 (Ws_h)
__global__ __launch_bounds__(256) void k_transpose(const float* __restrict__ W1, const float* __restrict__ W2,
                                                   unsigned short* __restrict__ Bt){
  const float* W = blockIdx.z ? W2 : W1;
  int nbase = blockIdx.z * 1024;
  __shared__ float tile[32][33];
  int k0 = blockIdx.y*32, n0 = blockIdx.x*32;
  int tx = threadIdx.x & 31, ty = threadIdx.x >> 5;  // ty 0..7
  for (int i = 0; i < 32; i += 8)
    tile[ty+i][tx] = W[(size_t)(k0+ty+i)*1024 + n0+tx];
  __syncthreads();
  for (int i = 0; i < 32; i += 8)
    Bt[(size_t)(nbase+n0+ty+i)*1024 + k0+tx] = f2bf(tile[tx][ty+i]);
}

// W_V1 [512][50000] fp32 -> W_V1T_bf [50048][512] bf16 (zero-padded rows)
__global__ __launch_bounds__(256) void k_tr_v1(const float* __restrict__ W_V1, unsigned short* __restrict__ Bt){
  __shared__ float tile[64][65];
  int n0 = blockIdx.x*64, k0 = blockIdx.y*64;
  int c = threadIdx.x & 63, r = threadIdx.x >> 6;  // r 0..3
  #pragma unroll
  for (int i = 0; i < 64; i += 4){
    int n = n0 + c;
    tile[r+i][c] = (n < Vn) ? W_V1[(size_t)(k0+r+i)*Vn + n] : 0.f;
  }
  __syncthreads();
  #pragma unroll
  for (int i = 0; i < 64; i += 4)
    Bt[(size_t)(n0+r+i)*512 + k0 + c] = f2bf(tile[c][r+i]);
}

// ---------------- small dense chain ----------------
__global__ __launch_bounds__(256) void k_x(const float* __restrict__ x_t, const float* __restrict__ ct_e,
                                           const float* __restrict__ W_xc, const float* __restrict__ b_xc,
                                           float* __restrict__ x){
  int b = blockIdx.x, e = threadIdx.x;
  float acc = b_xc[e];
  for (int k = 0; k < 256;  ++k) acc += x_t[b*256+k]  * W_xc[k*256+e];
  for (int k = 0; k < 1024; ++k) acc += ct_e[b*1024+k]* W_xc[(256+k)*256+e];
  x[b*256+e] = acc;
}

__global__ __launch_bounds__(256) void k_lstm(const float* __restrict__ x, const float* __restrict__ s_h,
                                              const float* __restrict__ s_c,
                                              const float* __restrict__ W_ih, const float* __restrict__ W_hh,
                                              const float* __restrict__ b_ih, const float* __restrict__ b_hh,
                                              float* __restrict__ h_out, float* __restrict__ c_out){
  int b = blockIdx.x;
  int j = threadIdx.x + blockIdx.y*256;   // 0..511
  float gi = b_ih[j]      + b_hh[j];
  float gf = b_ih[512+j]  + b_hh[512+j];
  float gg = b_ih[1024+j] + b_hh[1024+j];
  float go = b_ih[1536+j] + b_hh[1536+j];
  for (int k = 0; k < 256; ++k){
    float xv = x[b*256+k]; const float* w = &W_ih[(size_t)k*2048];
    gi += xv*w[j]; gf += xv*w[512+j]; gg += xv*w[1024+j]; go += xv*w[1536+j];
  }
  for (int k = 0; k < 512; ++k){
    float hv = s_h[b*512+k]; const float* w = &W_hh[(size_t)k*2048];
    gi += hv*w[j]; gf += hv*w[512+j]; gg += hv*w[1024+j]; go += hv*w[1536+j];
  }
  float c = sigf(gf)*s_c[b*512+j] + sigf(gi)*tanh_fast(gg);
  float h = sigf(go)*tanh_fast(c);
  h_out[b*512+j] = h;
  c_out[b*512+j] = c;
}

__global__ __launch_bounds__(256) void k_qe(const float* __restrict__ h, const float* __restrict__ c,
                                            const float* __restrict__ We_s, const float* __restrict__ be_s,
                                            float* __restrict__ q_e){
  int b = blockIdx.x;
  int d = threadIdx.x + blockIdx.y*256;   // 0..1023
  float acc = be_s[d];
  for (int k = 0; k < 512; ++k) acc += h[b*512+k]*We_s[(size_t)k*1024 + d];
  for (int k = 0; k < 512; ++k) acc += c[b*512+k]*We_s[(size_t)(512+k)*1024 + d];
  q_e[b*1024+d] = acc;
}

__global__ __launch_bounds__(256) void k_qd(const float* __restrict__ h, const float* __restrict__ Wd_s,
                                            const float* __restrict__ bd_s, float* __restrict__ q_d){
  int b = blockIdx.x;
  int j = threadIdx.x + blockIdx.y*256;   // 0..511
  float acc = bd_s[j];
  for (int k = 0; k < 512; ++k) acc += h[b*512+k]*Wd_s[(size_t)k*512 + j];
  q_d[b*512+j] = acc;
}

// ---------------- the big fused dual-GEMM (m97 pattern) ----------------
__global__ __launch_bounds__(256,3) void k_gemm_big(
    const unsigned short* __restrict__ Abf,   // [25600][1024]
    const unsigned short* __restrict__ Btbf,  // [2048][1024]
    const float* __restrict__ q_e,            // [64][1024]
    const float* __restrict__ bs_h, const float* __restrict__ ve,
    const float* __restrict__ vs1,  const float* __restrict__ vs2,
    float* __restrict__ et_raw, float* __restrict__ au_raw, float* __restrict__ et2_acc)
{
  __shared__ __align__(16) unsigned short As[128*64];
  __shared__ __align__(16) unsigned short Bs[128*64];
  __shared__ float bias2_s[2][128];
  __shared__ float vv_s[128];
  __shared__ float rowW_s[128];
  __shared__ unsigned char rowSel_s[128];

  const int tid = threadIdx.x;
  const int bn = blockIdx.x, bm = blockIdx.y;
  const int r0  = bm*128;
  const int n0g = bn*128;
  const bool etmode = (n0g < 1024);
  const int dbase = etmode ? n0g : (n0g - 1024);
  const int b_lo = r0/400;
  const int b_hi = min(b_lo+1, 63);
  const bool bcross = (r0/400) != ((r0+127)/400);

  if (tid < 128){
    int r = r0 + tid;
    int bb = r/400;
    rowSel_s[tid] = (unsigned char)(bb - b_lo);
    rowW_s[tid]   = vs2[r - bb*400];
    vv_s[tid]     = etmode ? ve[dbase+tid] : vs1[dbase+tid];
    bias2_s[0][tid] = etmode ? q_e[b_lo*1024 + dbase + tid] : bs_h[dbase+tid];
    bias2_s[1][tid] = etmode ? q_e[b_hi*1024 + dbase + tid] : bs_h[dbase+tid];
  }

  const int w = tid >> 6, lane = tid & 63;
  const int wm = w & 1, wn = w >> 1;
  const int lr = lane & 15, lq = lane >> 4;

  const int srow = lane >> 3, scol = (lane & 7)*8;
  const unsigned short* gA0 = Abf  + (size_t)(r0  + w*32 + srow)*1024 + scol;
  const unsigned short* gB0 = Btbf + (size_t)(n0g + w*32 + srow)*1024 + scol;
  unsigned short* lA0 = As + w*32*64;
  unsigned short* lB0 = Bs + w*32*64;

  f32x4 acc[4][4];
  #pragma unroll
  for (int i = 0; i < 4; ++i)
    #pragma unroll
    for (int j = 0; j < 4; ++j){ acc[i][j][0]=0.f; acc[i][j][1]=0.f; acc[i][j][2]=0.f; acc[i][j][3]=0.f; }

  for (int kt = 0; kt < 16; ++kt){
    __syncthreads();
    #pragma unroll
    for (int q = 0; q < 4; ++q){
      async16(gA0 + (size_t)q*8*1024 + kt*64, lA0 + q*512);
      async16(gB0 + (size_t)q*8*1024 + kt*64, lB0 + q*512);
    }
    __syncthreads();
    #pragma unroll
    for (int kk = 0; kk < 2; ++kk){
      bf16x8 a[4], b[4];
      #pragma unroll
      for (int i = 0; i < 4; ++i){
        a[i] = *(const bf16x8*)&As[(wm*64 + i*16 + lr)*64 + kk*32 + lq*8];
        b[i] = *(const bf16x8*)&Bs[(wn*64 + i*16 + lr)*64 + kk*32 + lq*8];
      }
      #pragma unroll
      for (int mt = 0; mt < 4; ++mt)
        #pragma unroll
        for (int nt = 0; nt < 4; ++nt)
          acc[mt][nt] = __builtin_amdgcn_mfma_f32_16x16x32_bf16(a[mt], b[nt], acc[mt][nt], 0, 0, 0);
    }
  }

  // ---- register epilogue ----
  float vvr[4], bias0[4], bias1[4];
  #pragma unroll
  for (int nt = 0; nt < 4; ++nt){
    int n = wn*64 + nt*16 + lr;
    vvr[nt]   = vv_s[n];
    bias0[nt] = bias2_s[0][n];
    bias1[nt] = bias2_s[1][n];
  }

  float rowdot[16];
  float colacc[4][2];
  #pragma unroll
  for (int nt = 0; nt < 4; ++nt){ colacc[nt][0]=0.f; colacc[nt][1]=0.f; }

  #pragma unroll
  for (int mt = 0; mt < 4; ++mt){
    #pragma unroll
    for (int v = 0; v < 4; ++v){
      int m = wm*64 + mt*16 + lq*4 + v;
      int sel = rowSel_s[m];
      float rw = rowW_s[m];
      float rd = 0.f;
      #pragma unroll
      for (int nt = 0; nt < 4; ++nt){
        float t = tanh_fast(acc[mt][nt][v] + (sel ? bias1[nt] : bias0[nt]));
        rd += t * vvr[nt];
        if (!etmode) colacc[nt][sel] += t * rw;
      }
      rowdot[mt*4+v] = rd;
    }
  }

  #pragma unroll
  for (int i = 0; i < 16; ++i){
    float s = rowdot[i];
    s += __shfl_xor(s,1); s += __shfl_xor(s,2); s += __shfl_xor(s,4); s += __shfl_xor(s,8);
    rowdot[i] = s;
  }
  if (lr == 0){
    float* dst = etmode ? et_raw : au_raw;
    #pragma unroll
    for (int i = 0; i < 16; ++i){
      int m = wm*64 + (i>>2)*16 + lq*4 + (i&3);
      atomicAdd(&dst[r0+m], rowdot[i]);
    }
  }

  if (!etmode){
    #pragma unroll
    for (int nt = 0; nt < 4; ++nt){
      #pragma unroll
      for (int s = 0; s < 2; ++s){
        float c = colacc[nt][s];
        c += __shfl_xor(c,16); c += __shfl_xor(c,32);
        if (lq == 0 && (s == 0 || bcross)){
          int n = wn*64 + nt*16 + lr;
          atomicAdd(&et2_acc[(b_lo+s)*1024 + dbase + n], c);
        }
      }
    }
  }
}

// ---------------- attention normalizations ----------------
__global__ __launch_bounds__(512) void k_attn_norm(const float* __restrict__ et_raw, const float* __restrict__ au_raw,
                                                   const float* __restrict__ et2_acc,
                                                   const float* __restrict__ sumts, const float* __restrict__ mask,
                                                   float* __restrict__ o_sumn, float* __restrict__ o_au,
                                                   float* __restrict__ o_et2, float* __restrict__ at_ws){
  int b = blockIdx.x, tid = threadIdx.x;
  __shared__ float red[512];
  float w = 0.f;
  if (tid < 400){
    float e  = __expf(et_raw[b*400+tid]);
    float st = sumts[b*400+tid];
    o_sumn[b*400+tid] = st + e;
    w = (e/st) * mask[b*400+tid];
  }
  red[tid] = w; __syncthreads();
  for (int s = 256; s > 0; s >>= 1){ if (tid < s) red[tid] += red[tid+s]; __syncthreads(); }
  float invw = 1.0f/red[0];
  __syncthreads();
  if (tid < 400) at_ws[b*400+tid] = w*invw;

  float a = 0.f;
  if (tid < 400) a = sigf(au_raw[b*400+tid]) * mask[b*400+tid];
  red[tid] = a; __syncthreads();
  for (int s = 256; s > 0; s >>= 1){ if (tid < s) red[tid] += red[tid+s]; __syncthreads(); }
  float inva = 1.0f/red[0];
  if (tid < 400) o_au[b*400+tid] = a*inva;

  for (int d = tid; d < 1024; d += 512) o_et2[b*1024+d] = sigf(et2_acc[b*1024+d]);
}

__global__ __launch_bounds__(256) void k_cte(const unsigned short* __restrict__ Abf, const float* __restrict__ at_ws,
                                             float* __restrict__ o_cte){
  int b = blockIdx.y;
  int d = blockIdx.x*256 + threadIdx.x;
  float acc = 0.f;
  for (int t = 0; t < 400; ++t)
    acc += at_ws[b*400+t] * bf2f(Abf[((size_t)(b*400+t))*1024 + d]);
  o_cte[b*1024+d] = acc;
}

// ---------------- intra-decoder attention ----------------
__global__ __launch_bounds__(256) void k_ed(const float* __restrict__ prev_s, const float* __restrict__ Wd_prev,
                                            const float* __restrict__ q_d, const float* __restrict__ vd,
                                            float* __restrict__ tmp_ed){
  int b = blockIdx.y;
  int j = (blockIdx.x & 1)*256 + threadIdx.x;
  int taub = (blockIdx.x >> 1)*25;
  float acc[25];
  #pragma unroll
  for (int t = 0; t < 25; ++t) acc[t] = 0.f;
  const float* ps = &prev_s[((size_t)b*50 + taub)*512];
  for (int k = 0; k < 512; ++k){
    float wv = Wd_prev[(size_t)k*512 + j];
    #pragma unroll
    for (int t = 0; t < 25; ++t) acc[t] += ps[(size_t)t*512 + k] * wv;
  }
  float qv = q_d[b*512+j], vdj = vd[j];
  #pragma unroll
  for (int t = 0; t < 25; ++t)
    tmp_ed[((size_t)b*50 + taub + t)*512 + j] = tanh_fast(acc[t] + qv) * vdj;
}

__global__ __launch_bounds__(512) void k_ctd(const float* __restrict__ tmp_ed, const float* __restrict__ prev_s,
                                             float* __restrict__ ct_d){
  int b = blockIdx.x, tid = threadIdx.x;
  __shared__ float ed_s[50];
  __shared__ float ad_s[50];
  if (tid < 400){
    int tau = tid >> 3, part = tid & 7;
    const float* tp = &tmp_ed[((size_t)b*50 + tau)*512 + part*64];
    float p = 0.f;
    for (int j = 0; j < 64; ++j) p += tp[j];
    p += __shfl_xor(p, 1); p += __shfl_xor(p, 2); p += __shfl_xor(p, 4);
    if (part == 0) ed_s[tau] = p;
  }
  __syncthreads();
  if (tid == 0){
    float mx = -1e30f;
    for (int t = 0; t < 50; ++t) mx = fmaxf(mx, ed_s[t]);
    float se = 0.f;
    for (int t = 0; t < 50; ++t){ float e = __expf(ed_s[t]-mx); ad_s[t] = e; se += e; }
    float inv = 1.f/se;
    for (int t = 0; t < 50; ++t) ad_s[t] *= inv;
  }
  __syncthreads();
  float acc = 0.f;
  for (int t = 0; t < 50; ++t) acc += ad_s[t]*prev_s[((size_t)b*50 + t)*512 + tid];
  ct_d[b*512+tid] = acc;
}

// ---------------- p_gen / out / logits / softmax / scatter ----------------
__global__ __launch_bounds__(256) void k_pgen(const float* __restrict__ cte, const float* __restrict__ ctd,
                                              const float* __restrict__ h, const float* __restrict__ c,
                                              const float* __restrict__ et2,
                                              const float* __restrict__ w_pg_cte, const float* __restrict__ w_pg_ctd,
                                              const float* __restrict__ w_pg_st, const float* __restrict__ w_pg_em,
                                              const float* __restrict__ b_pg_st, float* __restrict__ p_gen){
  int b = blockIdx.x, tid = threadIdx.x;
  float s = 0.f;
  for (int d = tid; d < 1024; d += 256) s += cte[b*1024+d]*w_pg_cte[d] + et2[b*1024+d]*w_pg_em[d];
  for (int d = tid; d < 512;  d += 256) s += ctd[b*512+d]*w_pg_ctd[d] + h[b*512+d]*w_pg_st[d] + c[b*512+d]*w_pg_st[512+d];
  __shared__ float red[256];
  red[tid] = s; __syncthreads();
  for (int k = 128; k > 0; k >>= 1){ if (tid < k) red[tid] += red[tid+k]; __syncthreads(); }
  if (tid == 0) p_gen[b] = sigf(red[0] + b_pg_st[0]);
}

// out_vec in bf16 (consumed only by the logits MFMA GEMM)
__global__ __launch_bounds__(256) void k_outvec(const float* __restrict__ h, const float* __restrict__ cte,
                                                const float* __restrict__ ctd, const float* __restrict__ et2,
                                                const float* __restrict__ W_V, const float* __restrict__ b_V,
                                                unsigned short* __restrict__ out_vec_bf){
  int b = blockIdx.y;
  int j = blockIdx.x*256 + threadIdx.x;   // 0..511
  float acc = b_V[j];
  for (int k = 0; k < 512;  ++k) acc += h[b*512+k]  *W_V[(size_t)k*512 + j];
  for (int k = 0; k < 1024; ++k) acc += cte[b*1024+k]*W_V[(size_t)(512+k)*512 + j];
  for (int k = 0; k < 512;  ++k) acc += ctd[b*512+k]*W_V[(size_t)(1536+k)*512 + j];
  for (int k = 0; k < 1024; ++k) acc += et2[b*1024+k]*W_V[(size_t)(2048+k)*512 + j];
  out_vec_bf[b*512+j] = f2bf(acc);
}

// logits[64][50000] = out_vec_bf[64][512] @ W_V1T_bf^T ; MFMA, M=64, N=64/block, K=512
__global__ __launch_bounds__(256) void k_logits_mfma(const unsigned short* __restrict__ Abf,  // [64][512]
                                                     const unsigned short* __restrict__ Btbf, // [50048][512]
                                                     const float* __restrict__ b_V1, float* __restrict__ logits){
  __shared__ __align__(16) unsigned short As[64*64];
  __shared__ __align__(16) unsigned short Bs[64*64];
  const int tid = threadIdx.x;
  const int n0 = blockIdx.x*64;
  const int w = tid >> 6, lane = tid & 63;
  const int lr = lane & 15, lq = lane >> 4;

  const int srow = lane >> 3, scol = (lane & 7)*8;   // 8 rows x 64 cols per async group
  const unsigned short* gA0 = Abf  + (size_t)(w*16 + srow)*512 + scol;
  const unsigned short* gB0 = Btbf + (size_t)(n0 + w*16 + srow)*512 + scol;
  unsigned short* lA0 = As + w*16*64;
  unsigned short* lB0 = Bs + w*16*64;

  f32x4 acc[4];
  #pragma unroll
  for (int i = 0; i < 4; ++i){ acc[i][0]=0.f; acc[i][1]=0.f; acc[i][2]=0.f; acc[i][3]=0.f; }

  for (int kt = 0; kt < 8; ++kt){
    __syncthreads();
    #pragma unroll
    for (int q = 0; q < 2; ++q){
      async16(gA0 + (size_t)q*8*512 + kt*64, lA0 + q*512);
      async16(gB0 + (size_t)q*8*512 + kt*64, lB0 + q*512);
    }
    __syncthreads();
    #pragma unroll
    for (int kk = 0; kk < 2; ++kk){
      bf16x8 a[4], b;
      #pragma unroll
      for (int i = 0; i < 4; ++i)
        a[i] = *(const bf16x8*)&As[(i*16 + lr)*64 + kk*32 + lq*8];
      b = *(const bf16x8*)&Bs[(w*16 + lr)*64 + kk*32 + lq*8];
      #pragma unroll
      for (int mt = 0; mt < 4; ++mt)
        acc[mt] = __builtin_amdgcn_mfma_f32_16x16x32_bf16(a[mt], b, acc[mt], 0, 0, 0);
    }
  }

  int n = n0 + w*16 + lr;
  if (n < Vn){
    float bb = b_V1[n];
    #pragma unroll
    for (int mt = 0; mt < 4; ++mt)
      #pragma unroll
      for (int v = 0; v < 4; ++v){
        int m = mt*16 + lq*4 + v;
        logits[(size_t)m*Vn + n] = acc[mt][v] + bb;
      }
  }
}

__global__ __launch_bounds__(1024) void k_softmax_final(const float* __restrict__ logits, const float* __restrict__ p_gen,
                                                        float* __restrict__ final_out){
  int b = blockIdx.x, tid = threadIdx.x;
  __shared__ float red[1024];
  const float* lrow = &logits[(size_t)b*Vn];
  float mx = -1e30f;
  for (int v = tid; v < Vn; v += 1024) mx = fmaxf(mx, lrow[v]);
  red[tid] = mx; __syncthreads();
  for (int s = 512; s > 0; s >>= 1){ if (tid < s) red[tid] = fmaxf(red[tid], red[tid+s]); __syncthreads(); }
  mx = red[0]; __syncthreads();
  float se = 0.f;
  for (int v = tid; v < Vn; v += 1024) se += __expf(lrow[v]-mx);
  red[tid] = se; __syncthreads();
  for (int s = 512; s > 0; s >>= 1){ if (tid < s) red[tid] += red[tid+s]; __syncthreads(); }
  float scale = p_gen[b]/red[0];
  float* frow = &final_out[(size_t)b*VEXTn];
  for (int v = tid; v < Vn; v += 1024) frow[v] = __expf(lrow[v]-mx)*scale;
  for (int v = Vn+tid; v < VEXTn; v += 1024) frow[v] = 0.f;
}

__global__ __launch_bounds__(256) void k_scatter(const int* __restrict__ ebev, const float* __restrict__ at_ws,
                                                 const float* __restrict__ p_gen, float* __restrict__ final_out){
  int i = blockIdx.x*256 + threadIdx.x;   // 25600
  int b = i / 400;
  float add = (1.f - p_gen[b]) * at_ws[i];
  atomicAdd(&final_out[(size_t)b*VEXTn + ebev[i]], add);
}

__global__ __launch_bounds__(256) void k_prevs(const float* __restrict__ prev_s, const float* __restrict__ h,
                                               float* __restrict__ o_prevs){
  int i = blockIdx.x*256 + threadIdx.x;   // 64*51*512 = 1,671,168
  int b = i / (51*512);
  int rem = i - b*51*512;
  int tau = rem >> 9, j = rem & 511;
  o_prevs[i] = (tau < 50) ? prev_s[((size_t)b*50 + tau)*512 + j] : h[b*512+j];
}

extern "C" void kernel_launch(void* const* d_in, const int* in_sizes, int n_in,
                              void* d_out, int out_size, void* d_ws, size_t ws_size,
                              hipStream_t stream)
{
  const float* x_t    = (const float*)d_in[0];
  const float* s_h    = (const float*)d_in[1];
  const float* s_c    = (const float*)d_in[2];
  const float* enc    = (const float*)d_in[3];
  const float* mask   = (const float*)d_in[4];
  const float* ct_e   = (const float*)d_in[5];
  const float* sumts  = (const float*)d_in[7];
  const float* prev_s = (const float*)d_in[8];
  const int*   ebev   = (const int*)d_in[9];
  const float* W_xc   = (const float*)d_in[10];
  const float* b_xc   = (const float*)d_in[11];
  const float* W_ih   = (const float*)d_in[12];
  const float* W_hh   = (const float*)d_in[13];
  const float* b_ih   = (const float*)d_in[14];
  const float* b_hh   = (const float*)d_in[15];
  const float* We_h   = (const float*)d_in[16];
  const float* We_s   = (const float*)d_in[17];
  const float* be_s   = (const float*)d_in[18];
  const float* ve     = (const float*)d_in[19];
  const float* Ws_h   = (const float*)d_in[20];
  const float* bs_h   = (const float*)d_in[21];
  const float* vs1    = (const float*)d_in[22];
  const float* vs2    = (const float*)d_in[23];
  const float* Wd_prev= (const float*)d_in[24];
  const float* Wd_s   = (const float*)d_in[25];
  const float* bd_s   = (const float*)d_in[26];
  const float* vd     = (const float*)d_in[27];
  const float* w_pg_em  = (const float*)d_in[28];
  const float* w_pg_cte = (const float*)d_in[29];
  const float* w_pg_ctd = (const float*)d_in[30];
  const float* w_pg_st  = (const float*)d_in[31];
  const float* b_pg_st  = (const float*)d_in[32];
  const float* W_V    = (const float*)d_in[33];
  const float* b_V    = (const float*)d_in[34];
  const float* W_V1   = (const float*)d_in[35];
  const float* b_V1   = (const float*)d_in[36];
  (void)in_sizes; (void)n_in; (void)out_size; (void)ws_size;

  float* out = (float*)d_out;
  float* o_final = out;                 // 64*50100 = 3,206,400
  float* o_h     = out + 3206400;       // 32768
  float* o_c     = out + 3239168;       // 32768
  float* o_cte   = out + 3271936;       // 65536
  float* o_au    = out + 3337472;       // 25600
  float* o_et2   = out + 3363072;       // 65536
  float* o_sumn  = out + 3428608;       // 25600
  float* o_prevs = out + 3454208;       // 1,671,168

  char* ws = (char*)d_ws;
  float* et_raw  = (float*)(ws + 0);          // zeroed
  float* au_raw  = (float*)(ws + 102400);     // zeroed
  float* et2_acc = (float*)(ws + 204800);     // zeroed
  float* at_ws   = (float*)(ws + 466944);
  float* x_ws    = (float*)(ws + 569344);
  float* q_e     = (float*)(ws + 634880);
  float* q_d     = (float*)(ws + 897024);
  float* ct_d    = (float*)(ws + 1028096);
  float* p_gen   = (float*)(ws + 1159168);
  float* logits  = (float*)(ws + 7844096);    // 12.8 MB
  // enc_bf region (52.4 MB) is reused by W_V1T_bf after k_cte (stream-serial)
  unsigned short* enc_bf  = (unsigned short*)(ws + 20644096);
  unsigned short* W_V1T   = (unsigned short*)(ws + 20644096);  // [50048][512] bf16 = 51.25 MB
  unsigned short* Bt_bf   = (unsigned short*)(ws + 73072896);  // 2048*1024 bf16
  float* tmp_ed  = (float*)(ws + 1290496);    // 6.5 MB
  unsigned short* out_vec_bf = (unsigned short*)(ws + 77267200); // 64*512 bf16

  hipMemsetAsync(ws, 0, 466944, stream);
  k_conv_enc<<<25600, 256, 0, stream>>>(enc, enc_bf);
  k_transpose<<<dim3(32,32,2), 256, 0, stream>>>(We_h, Ws_h, Bt_bf);
  k_x<<<64, 256, 0, stream>>>(x_t, ct_e, W_xc, b_xc, x_ws);
  k_lstm<<<dim3(64,2), 256, 0, stream>>>(x_ws, s_h, s_c, W_ih, W_hh, b_ih, b_hh, o_h, o_c);
  k_qe<<<dim3(64,4), 256, 0, stream>>>(o_h, o_c, We_s, be_s, q_e);
  k_qd<<<dim3(64,2), 256, 0, stream>>>(o_h, Wd_s, bd_s, q_d);
  k_gemm_big<<<dim3(16,200), 256, 0, stream>>>(enc_bf, Bt_bf, q_e, bs_h, ve, vs1, vs2,
                                               et_raw, au_raw, et2_acc);
  k_attn_norm<<<64, 512, 0, stream>>>(et_raw, au_raw, et2_acc, sumts, mask, o_sumn, o_au, o_et2, at_ws);
  k_cte<<<dim3(4,64), 256, 0, stream>>>(enc_bf, at_ws, o_cte);
  // enc_bf dead from here; its region becomes W_V1T
  k_tr_v1<<<dim3(782,8), 256, 0, stream>>>(W_V1, W_V1T);
  k_ed<<<dim3(4,64), 256, 0, stream>>>(prev_s, Wd_prev, q_d, vd, tmp_ed);
  k_ctd<<<64, 512, 0, stream>>>(tmp_ed, prev_s, ct_d);
  k_pgen<<<64, 256, 0, stream>>>(o_cte, ct_d, o_h, o_c, o_et2, w_pg_cte, w_pg_ctd, w_pg_st, w_pg_em, b_pg_st, p_gen);
  k_outvec<<<dim3(2,64), 256, 0, stream>>>(o_h, o_cte, ct_d, o_et2, W_V, b_V, out_vec_bf);
  k_logits_mfma<<<782, 256, 0, stream>>>(out_vec_bf, W_V1T, b_V1, logits);
  k_softmax_final<<<64, 1024, 0, stream>>>(logits, p_gen, o_final);
  k_scatter<<<100, 256, 0, stream>>>(ebev, at_ws, p_gen, o_final);
  k_prevs<<<6528, 256, 0, stream>>>(prev_s, o_h, o_prevs);
}

// Round 4
// 927.155 us; speedup vs baseline: 1.9047x; 1.2316x over previous
//
#include <hip/hip_runtime.h>
#include <stdint.h>

#define Bn 64
#define Tn 400
#define Hn 512
#define En 256
#define Vn 50000
#define NOOVn 100
#define TPn 50
#define H2n 1024
#define VEXTn (Vn+NOOVn)  // 50100
#define VPADn 50048       // 782*64

typedef __bf16 bf16x8 __attribute__((ext_vector_type(8)));
typedef float  f32x4  __attribute__((ext_vector_type(4)));

__device__ __forceinline__ float sigf(float x){ return 1.0f/(1.0f+__expf(-x)); }
__device__ __forceinline__ float tanh_fast(float x){
  float e = __expf(2.0f*x);
  return (e-1.0f)/(e+1.0f);
}

__device__ __forceinline__ unsigned short f2bf(float f){
  union { float f; uint32_t u; } v; v.f = f;
  uint32_t r = v.u + 0x7FFFu + ((v.u >> 16) & 1u);
  return (unsigned short)(r >> 16);
}
__device__ __forceinline__ float bf2f(unsigned short s){
  union { uint32_t u; float f; } v; v.u = ((uint32_t)s) << 16;
  return v.f;
}

__device__ __forceinline__ void async16(const void* g, void* l){
  __builtin_amdgcn_global_load_lds((__attribute__((address_space(1))) void*)g,
                                   (__attribute__((address_space(3))) void*)l, 16, 0, 0);
}

// ---------------- conversions ----------------
__global__ __launch_bounds__(256) void k_conv_enc(const float* __restrict__ enc, unsigned short* __restrict__ out){
  int i = blockIdx.x*256 + threadIdx.x;
  const float4* e4 = (const float4*)enc;
  float4 v = e4[i];
  ushort4 r;
  r.x = f2bf(v.x); r.y = f2bf(v.y); r.z = f2bf(v.z); r.w = f2bf(v.w);
  ((ushort4*)out)[i] = r;
}

// Bt[n][k] = W[k][n], n<1024 from W1 (We_h), n>=1024 from W2 (Ws_h)
__global__ __launch_bounds__(256) void k_transpose(const float* __restrict__ W1, const float* __restrict__ W2,
                                                   unsigned short* __restrict__ Bt){
  const float* W = blockIdx.z ? W2 : W1;
  int nbase = blockIdx.z * 1024;
  __shared__ float tile[32][33];
  int k0 = blockIdx.y*32, n0 = blockIdx.x*32;
  int tx = threadIdx.x & 31, ty = threadIdx.x >> 5;  // ty 0..7
  for (int i = 0; i < 32; i += 8)
    tile[ty+i][tx] = W[(size_t)(k0+ty+i)*1024 + n0+tx];
  __syncthreads();
  for (int i = 0; i < 32; i += 8)
    Bt[(size_t)(nbase+n0+ty+i)*1024 + k0+tx] = f2bf(tile[tx][ty+i]);
}

// W_V1 [512][50000] fp32 -> W_V1T_bf [50048][512] bf16 (zero-padded rows)
__global__ __launch_bounds__(256) void k_tr_v1(const float* __restrict__ W_V1, unsigned short* __restrict__ Bt){
  __shared__ float tile[64][65];
  int n0 = blockIdx.x*64, k0 = blockIdx.y*64;
  int c = threadIdx.x & 63, r = threadIdx.x >> 6;  // r 0..3
  #pragma unroll
  for (int i = 0; i < 64; i += 4){
    int n = n0 + c;
    tile[r+i][c] = (n < Vn) ? W_V1[(size_t)(k0+r+i)*Vn + n] : 0.f;
  }
  __syncthreads();
  #pragma unroll
  for (int i = 0; i < 64; i += 4)
    Bt[(size_t)(n0+r+i)*512 + k0 + c] = f2bf(tile[c][r+i]);
}

// ---------------- split-K GEMV chain (M=64, fp32 atomics) ----------------
// x_acc[b][n] = ([x_t | ct_e] @ W_xc)[b][n]   (no bias; folded downstream)
__global__ __launch_bounds__(256) void k_gemv_x(const float* __restrict__ x_t, const float* __restrict__ ct_e,
                                                const float* __restrict__ W_xc, float* __restrict__ x_acc){
  int n = threadIdx.x;            // 0..255
  int b = blockIdx.y;
  int k0 = blockIdx.z*256;        // z 0..4 (K=1280)
  float acc = 0.f;
  #pragma unroll 4
  for (int kk = 0; kk < 256; ++kk){
    int k = k0 + kk;
    float a = (k < 256) ? x_t[b*256+k] : ct_e[b*1024 + k - 256];
    acc += a * W_xc[(size_t)k*256 + n];
  }
  atomicAdd(&x_acc[b*256+n], acc);
}

// gates_acc[b][n] = (x+b_xc) @ W_ih + s_h @ W_hh   (n in [0,2048))
__global__ __launch_bounds__(256) void k_gemv_gates(const float* __restrict__ x_acc, const float* __restrict__ b_xc,
                                                    const float* __restrict__ s_h,
                                                    const float* __restrict__ W_ih, const float* __restrict__ W_hh,
                                                    float* __restrict__ gates_acc){
  int n = blockIdx.x*256 + threadIdx.x;  // 0..2047
  int b = blockIdx.y;
  int k0 = blockIdx.z*256;               // z 0..2 (K=768)
  float acc = 0.f;
  #pragma unroll 4
  for (int kk = 0; kk < 256; ++kk){
    int k = k0 + kk;
    float a; const float* wrow;
    if (k < 256){ a = x_acc[b*256+k] + b_xc[k]; wrow = &W_ih[(size_t)k*2048]; }
    else        { a = s_h[b*512 + k-256];       wrow = &W_hh[(size_t)(k-256)*2048]; }
    acc += a * wrow[n];
  }
  atomicAdd(&gates_acc[(size_t)b*2048 + n], acc);
}

__global__ __launch_bounds__(256) void k_lstm_act(const float* __restrict__ gates_acc,
                                                  const float* __restrict__ b_ih, const float* __restrict__ b_hh,
                                                  const float* __restrict__ s_c,
                                                  float* __restrict__ h_out, float* __restrict__ c_out){
  int b = blockIdx.y;
  int j = blockIdx.x*256 + threadIdx.x;  // 0..511
  const float* g = &gates_acc[(size_t)b*2048];
  float gi = g[j]      + b_ih[j]      + b_hh[j];
  float gf = g[512+j]  + b_ih[512+j]  + b_hh[512+j];
  float gg = g[1024+j] + b_ih[1024+j] + b_hh[1024+j];
  float go = g[1536+j] + b_ih[1536+j] + b_hh[1536+j];
  float c = sigf(gf)*s_c[b*512+j] + sigf(gi)*tanh_fast(gg);
  float h = sigf(go)*tanh_fast(c);
  h_out[b*512+j] = h;
  c_out[b*512+j] = c;
}

// qe_acc[b][n] = [h|c] @ We_s   (be_s folded into k_gemm_big)
__global__ __launch_bounds__(256) void k_gemv_qe(const float* __restrict__ h, const float* __restrict__ c,
                                                 const float* __restrict__ We_s, float* __restrict__ qe_acc){
  int n = blockIdx.x*256 + threadIdx.x;  // 0..1023
  int b = blockIdx.y;
  int k0 = blockIdx.z*256;               // z 0..3 (K=1024)
  float acc = 0.f;
  #pragma unroll 4
  for (int kk = 0; kk < 256; ++kk){
    int k = k0 + kk;
    float a = (k < 512) ? h[b*512+k] : c[b*512 + k-512];
    acc += a * We_s[(size_t)k*1024 + n];
  }
  atomicAdd(&qe_acc[b*1024+n], acc);
}

// qd_acc[b][n] = h @ Wd_s   (bd_s folded into k_ed)
__global__ __launch_bounds__(256) void k_gemv_qd(const float* __restrict__ h, const float* __restrict__ Wd_s,
                                                 float* __restrict__ qd_acc){
  int n = blockIdx.x*256 + threadIdx.x;  // 0..511
  int b = blockIdx.y;
  int k0 = blockIdx.z*256;               // z 0..1 (K=512)
  float acc = 0.f;
  #pragma unroll 4
  for (int kk = 0; kk < 256; ++kk){
    int k = k0 + kk;
    acc += h[b*512+k] * Wd_s[(size_t)k*512 + n];
  }
  atomicAdd(&qd_acc[b*512+n], acc);
}

// ov_acc[b][n] = [h|cte|ctd|et2] @ W_V   (b_V folded into k_outvec_fin)
__global__ __launch_bounds__(256) void k_gemv_outvec(const float* __restrict__ h, const float* __restrict__ cte,
                                                     const float* __restrict__ ctd, const float* __restrict__ et2,
                                                     const float* __restrict__ W_V, float* __restrict__ ov_acc){
  int n = blockIdx.x*256 + threadIdx.x;  // 0..511
  int b = blockIdx.y;
  int z = blockIdx.z;                    // 0..5, Kc=512 aligned with segment bounds
  const float* base;
  switch(z){
    case 0:  base = &h[b*512];        break;
    case 1:  base = &cte[b*1024];     break;
    case 2:  base = &cte[b*1024+512]; break;
    case 3:  base = &ctd[b*512];      break;
    case 4:  base = &et2[b*1024];     break;
    default: base = &et2[b*1024+512]; break;
  }
  const float* wrow = &W_V[(size_t)z*512*512];
  float acc = 0.f;
  #pragma unroll 4
  for (int kk = 0; kk < 512; ++kk)
    acc += base[kk] * wrow[(size_t)kk*512 + n];
  atomicAdd(&ov_acc[b*512+n], acc);
}

__global__ __launch_bounds__(256) void k_outvec_fin(const float* __restrict__ ov_acc, const float* __restrict__ b_V,
                                                    unsigned short* __restrict__ out_vec_bf){
  int i = blockIdx.x*256 + threadIdx.x;  // 32768
  int j = i & 511;
  out_vec_bf[i] = f2bf(ov_acc[i] + b_V[j]);
}

// ---------------- the big fused dual-GEMM (m97 pattern) ----------------
__global__ __launch_bounds__(256,3) void k_gemm_big(
    const unsigned short* __restrict__ Abf,   // [25600][1024]
    const unsigned short* __restrict__ Btbf,  // [2048][1024]
    const float* __restrict__ q_e,            // [64][1024] (no bias)
    const float* __restrict__ be_s,
    const float* __restrict__ bs_h, const float* __restrict__ ve,
    const float* __restrict__ vs1,  const float* __restrict__ vs2,
    float* __restrict__ et_raw, float* __restrict__ au_raw, float* __restrict__ et2_acc)
{
  __shared__ __align__(16) unsigned short As[128*64];
  __shared__ __align__(16) unsigned short Bs[128*64];
  __shared__ float bias2_s[2][128];
  __shared__ float vv_s[128];
  __shared__ float rowW_s[128];
  __shared__ unsigned char rowSel_s[128];

  const int tid = threadIdx.x;
  const int bn = blockIdx.x, bm = blockIdx.y;
  const int r0  = bm*128;
  const int n0g = bn*128;
  const bool etmode = (n0g < 1024);
  const int dbase = etmode ? n0g : (n0g - 1024);
  const int b_lo = r0/400;
  const int b_hi = min(b_lo+1, 63);
  const bool bcross = (r0/400) != ((r0+127)/400);

  if (tid < 128){
    int r = r0 + tid;
    int bb = r/400;
    rowSel_s[tid] = (unsigned char)(bb - b_lo);
    rowW_s[tid]   = vs2[r - bb*400];
    vv_s[tid]     = etmode ? ve[dbase+tid] : vs1[dbase+tid];
    bias2_s[0][tid] = etmode ? (q_e[b_lo*1024 + dbase + tid] + be_s[dbase+tid]) : bs_h[dbase+tid];
    bias2_s[1][tid] = etmode ? (q_e[b_hi*1024 + dbase + tid] + be_s[dbase+tid]) : bs_h[dbase+tid];
  }

  const int w = tid >> 6, lane = tid & 63;
  const int wm = w & 1, wn = w >> 1;
  const int lr = lane & 15, lq = lane >> 4;

  const int srow = lane >> 3, scol = (lane & 7)*8;
  const unsigned short* gA0 = Abf  + (size_t)(r0  + w*32 + srow)*1024 + scol;
  const unsigned short* gB0 = Btbf + (size_t)(n0g + w*32 + srow)*1024 + scol;
  unsigned short* lA0 = As + w*32*64;
  unsigned short* lB0 = Bs + w*32*64;

  f32x4 acc[4][4];
  #pragma unroll
  for (int i = 0; i < 4; ++i)
    #pragma unroll
    for (int j = 0; j < 4; ++j){ acc[i][j][0]=0.f; acc[i][j][1]=0.f; acc[i][j][2]=0.f; acc[i][j][3]=0.f; }

  for (int kt = 0; kt < 16; ++kt){
    __syncthreads();
    #pragma unroll
    for (int q = 0; q < 4; ++q){
      async16(gA0 + (size_t)q*8*1024 + kt*64, lA0 + q*512);
      async16(gB0 + (size_t)q*8*1024 + kt*64, lB0 + q*512);
    }
    __syncthreads();
    #pragma unroll
    for (int kk = 0; kk < 2; ++kk){
      bf16x8 a[4], b[4];
      #pragma unroll
      for (int i = 0; i < 4; ++i){
        a[i] = *(const bf16x8*)&As[(wm*64 + i*16 + lr)*64 + kk*32 + lq*8];
        b[i] = *(const bf16x8*)&Bs[(wn*64 + i*16 + lr)*64 + kk*32 + lq*8];
      }
      #pragma unroll
      for (int mt = 0; mt < 4; ++mt)
        #pragma unroll
        for (int nt = 0; nt < 4; ++nt)
          acc[mt][nt] = __builtin_amdgcn_mfma_f32_16x16x32_bf16(a[mt], b[nt], acc[mt][nt], 0, 0, 0);
    }
  }

  // ---- register epilogue ----
  float vvr[4], bias0[4], bias1[4];
  #pragma unroll
  for (int nt = 0; nt < 4; ++nt){
    int n = wn*64 + nt*16 + lr;
    vvr[nt]   = vv_s[n];
    bias0[nt] = bias2_s[0][n];
    bias1[nt] = bias2_s[1][n];
  }

  float rowdot[16];
  float colacc[4][2];
  #pragma unroll
  for (int nt = 0; nt < 4; ++nt){ colacc[nt][0]=0.f; colacc[nt][1]=0.f; }

  #pragma unroll
  for (int mt = 0; mt < 4; ++mt){
    #pragma unroll
    for (int v = 0; v < 4; ++v){
      int m = wm*64 + mt*16 + lq*4 + v;
      int sel = rowSel_s[m];
      float rw = rowW_s[m];
      float rd = 0.f;
      #pragma unroll
      for (int nt = 0; nt < 4; ++nt){
        float t = tanh_fast(acc[mt][nt][v] + (sel ? bias1[nt] : bias0[nt]));
        rd += t * vvr[nt];
        if (!etmode) colacc[nt][sel] += t * rw;
      }
      rowdot[mt*4+v] = rd;
    }
  }

  #pragma unroll
  for (int i = 0; i < 16; ++i){
    float s = rowdot[i];
    s += __shfl_xor(s,1); s += __shfl_xor(s,2); s += __shfl_xor(s,4); s += __shfl_xor(s,8);
    rowdot[i] = s;
  }
  if (lr == 0){
    float* dst = etmode ? et_raw : au_raw;
    #pragma unroll
    for (int i = 0; i < 16; ++i){
      int m = wm*64 + (i>>2)*16 + lq*4 + (i&3);
      atomicAdd(&dst[r0+m], rowdot[i]);
    }
  }

  if (!etmode){
    #pragma unroll
    for (int nt = 0; nt < 4; ++nt){
      #pragma unroll
      for (int s = 0; s < 2; ++s){
        float c = colacc[nt][s];
        c += __shfl_xor(c,16); c += __shfl_xor(c,32);
        if (lq == 0 && (s == 0 || bcross)){
          int n = wn*64 + nt*16 + lr;
          atomicAdd(&et2_acc[(b_lo+s)*1024 + dbase + n], c);
        }
      }
    }
  }
}

// ---------------- attention normalizations ----------------
__global__ __launch_bounds__(512) void k_attn_norm(const float* __restrict__ et_raw, const float* __restrict__ au_raw,
                                                   const float* __restrict__ et2_acc,
                                                   const float* __restrict__ sumts, const float* __restrict__ mask,
                                                   float* __restrict__ o_sumn, float* __restrict__ o_au,
                                                   float* __restrict__ o_et2, float* __restrict__ at_ws){
  int b = blockIdx.x, tid = threadIdx.x;
  __shared__ float red[512];
  float w = 0.f;
  if (tid < 400){
    float e  = __expf(et_raw[b*400+tid]);
    float st = sumts[b*400+tid];
    o_sumn[b*400+tid] = st + e;
    w = (e/st) * mask[b*400+tid];
  }
  red[tid] = w; __syncthreads();
  for (int s = 256; s > 0; s >>= 1){ if (tid < s) red[tid] += red[tid+s]; __syncthreads(); }
  float invw = 1.0f/red[0];
  __syncthreads();
  if (tid < 400) at_ws[b*400+tid] = w*invw;

  float a = 0.f;
  if (tid < 400) a = sigf(au_raw[b*400+tid]) * mask[b*400+tid];
  red[tid] = a; __syncthreads();
  for (int s = 256; s > 0; s >>= 1){ if (tid < s) red[tid] += red[tid+s]; __syncthreads(); }
  float inva = 1.0f/red[0];
  if (tid < 400) o_au[b*400+tid] = a*inva;

  for (int d = tid; d < 1024; d += 512) o_et2[b*1024+d] = sigf(et2_acc[b*1024+d]);
}

__global__ __launch_bounds__(256) void k_cte(const unsigned short* __restrict__ Abf, const float* __restrict__ at_ws,
                                             float* __restrict__ o_cte){
  int b = blockIdx.y;
  int d = blockIdx.x*256 + threadIdx.x;
  float acc = 0.f;
  for (int t = 0; t < 400; ++t)
    acc += at_ws[b*400+t] * bf2f(Abf[((size_t)(b*400+t))*1024 + d]);
  o_cte[b*1024+d] = acc;
}

// ---------------- intra-decoder attention ----------------
__global__ __launch_bounds__(256) void k_ed(const float* __restrict__ prev_s, const float* __restrict__ Wd_prev,
                                            const float* __restrict__ q_d, const float* __restrict__ bd_s,
                                            const float* __restrict__ vd, float* __restrict__ tmp_ed){
  int b = blockIdx.y;
  int j = (blockIdx.x & 1)*256 + threadIdx.x;
  int taub = (blockIdx.x >> 1)*25;
  float acc[25];
  #pragma unroll
  for (int t = 0; t < 25; ++t) acc[t] = 0.f;
  const float* ps = &prev_s[((size_t)b*50 + taub)*512];
  for (int k = 0; k < 512; ++k){
    float wv = Wd_prev[(size_t)k*512 + j];
    #pragma unroll
    for (int t = 0; t < 25; ++t) acc[t] += ps[(size_t)t*512 + k] * wv;
  }
  float qv = q_d[b*512+j] + bd_s[j], vdj = vd[j];
  #pragma unroll
  for (int t = 0; t < 25; ++t)
    tmp_ed[((size_t)b*50 + taub + t)*512 + j] = tanh_fast(acc[t] + qv) * vdj;
}

__global__ __launch_bounds__(512) void k_ctd(const float* __restrict__ tmp_ed, const float* __restrict__ prev_s,
                                             float* __restrict__ ct_d){
  int b = blockIdx.x, tid = threadIdx.x;
  __shared__ float ed_s[50];
  __shared__ float ad_s[50];
  if (tid < 400){
    int tau = tid >> 3, part = tid & 7;
    const float* tp = &tmp_ed[((size_t)b*50 + tau)*512 + part*64];
    float p = 0.f;
    for (int j = 0; j < 64; ++j) p += tp[j];
    p += __shfl_xor(p, 1); p += __shfl_xor(p, 2); p += __shfl_xor(p, 4);
    if (part == 0) ed_s[tau] = p;
  }
  __syncthreads();
  if (tid == 0){
    float mx = -1e30f;
    for (int t = 0; t < 50; ++t) mx = fmaxf(mx, ed_s[t]);
    float se = 0.f;
    for (int t = 0; t < 50; ++t){ float e = __expf(ed_s[t]-mx); ad_s[t] = e; se += e; }
    float inv = 1.f/se;
    for (int t = 0; t < 50; ++t) ad_s[t] *= inv;
  }
  __syncthreads();
  float acc = 0.f;
  for (int t = 0; t < 50; ++t) acc += ad_s[t]*prev_s[((size_t)b*50 + t)*512 + tid];
  ct_d[b*512+tid] = acc;
}

// ---------------- p_gen / logits / softmax / scatter ----------------
__global__ __launch_bounds__(256) void k_pgen(const float* __restrict__ cte, const float* __restrict__ ctd,
                                              const float* __restrict__ h, const float* __restrict__ c,
                                              const float* __restrict__ et2,
                                              const float* __restrict__ w_pg_cte, const float* __restrict__ w_pg_ctd,
                                              const float* __restrict__ w_pg_st, const float* __restrict__ w_pg_em,
                                              const float* __restrict__ b_pg_st, float* __restrict__ p_gen){
  int b = blockIdx.x, tid = threadIdx.x;
  float s = 0.f;
  for (int d = tid; d < 1024; d += 256) s += cte[b*1024+d]*w_pg_cte[d] + et2[b*1024+d]*w_pg_em[d];
  for (int d = tid; d < 512;  d += 256) s += ctd[b*512+d]*w_pg_ctd[d] + h[b*512+d]*w_pg_st[d] + c[b*512+d]*w_pg_st[512+d];
  __shared__ float red[256];
  red[tid] = s; __syncthreads();
  for (int k = 128; k > 0; k >>= 1){ if (tid < k) red[tid] += red[tid+k]; __syncthreads(); }
  if (tid == 0) p_gen[b] = sigf(red[0] + b_pg_st[0]);
}

// logits[64][50000] = out_vec_bf[64][512] @ W_V1T_bf^T ; MFMA, M=64, N=64/block, K=512
__global__ __launch_bounds__(256) void k_logits_mfma(const unsigned short* __restrict__ Abf,  // [64][512]
                                                     const unsigned short* __restrict__ Btbf, // [50048][512]
                                                     const float* __restrict__ b_V1, float* __restrict__ logits){
  __shared__ __align__(16) unsigned short As[64*64];
  __shared__ __align__(16) unsigned short Bs[64*64];
  const int tid = threadIdx.x;
  const int n0 = blockIdx.x*64;
  const int w = tid >> 6, lane = tid & 63;
  const int lr = lane & 15, lq = lane >> 4;

  const int srow = lane >> 3, scol = (lane & 7)*8;
  const unsigned short* gA0 = Abf  + (size_t)(w*16 + srow)*512 + scol;
  const unsigned short* gB0 = Btbf + (size_t)(n0 + w*16 + srow)*512 + scol;
  unsigned short* lA0 = As + w*16*64;
  unsigned short* lB0 = Bs + w*16*64;

  f32x4 acc[4];
  #pragma unroll
  for (int i = 0; i < 4; ++i){ acc[i][0]=0.f; acc[i][1]=0.f; acc[i][2]=0.f; acc[i][3]=0.f; }

  for (int kt = 0; kt < 8; ++kt){
    __syncthreads();
    #pragma unroll
    for (int q = 0; q < 2; ++q){
      async16(gA0 + (size_t)q*8*512 + kt*64, lA0 + q*512);
      async16(gB0 + (size_t)q*8*512 + kt*64, lB0 + q*512);
    }
    __syncthreads();
    #pragma unroll
    for (int kk = 0; kk < 2; ++kk){
      bf16x8 a[4], b;
      #pragma unroll
      for (int i = 0; i < 4; ++i)
        a[i] = *(const bf16x8*)&As[(i*16 + lr)*64 + kk*32 + lq*8];
      b = *(const bf16x8*)&Bs[(w*16 + lr)*64 + kk*32 + lq*8];
      #pragma unroll
      for (int mt = 0; mt < 4; ++mt)
        acc[mt] = __builtin_amdgcn_mfma_f32_16x16x32_bf16(a[mt], b, acc[mt], 0, 0, 0);
    }
  }

  int n = n0 + w*16 + lr;
  if (n < Vn){
    float bb = b_V1[n];
    #pragma unroll
    for (int mt = 0; mt < 4; ++mt)
      #pragma unroll
      for (int v = 0; v < 4; ++v){
        int m = mt*16 + lq*4 + v;
        logits[(size_t)m*Vn + n] = acc[mt][v] + bb;
      }
  }
}

__global__ __launch_bounds__(1024) void k_softmax_final(const float* __restrict__ logits, const float* __restrict__ p_gen,
                                                        float* __restrict__ final_out){
  int b = blockIdx.x, tid = threadIdx.x;
  __shared__ float red[1024];
  const float* lrow = &logits[(size_t)b*Vn];
  float mx = -1e30f;
  for (int v = tid; v < Vn; v += 1024) mx = fmaxf(mx, lrow[v]);
  red[tid] = mx; __syncthreads();
  for (int s = 512; s > 0; s >>= 1){ if (tid < s) red[tid] = fmaxf(red[tid], red[tid+s]); __syncthreads(); }
  mx = red[0]; __syncthreads();
  float se = 0.f;
  for (int v = tid; v < Vn; v += 1024) se += __expf(lrow[v]-mx);
  red[tid] = se; __syncthreads();
  for (int s = 512; s > 0; s >>= 1){ if (tid < s) red[tid] += red[tid+s]; __syncthreads(); }
  float scale = p_gen[b]/red[0];
  float* frow = &final_out[(size_t)b*VEXTn];
  for (int v = tid; v < Vn; v += 1024) frow[v] = __expf(lrow[v]-mx)*scale;
  for (int v = Vn+tid; v < VEXTn; v += 1024) frow[v] = 0.f;
}

__global__ __launch_bounds__(256) void k_scatter(const int* __restrict__ ebev, const float* __restrict__ at_ws,
                                                 const float* __restrict__ p_gen, float* __restrict__ final_out){
  int i = blockIdx.x*256 + threadIdx.x;   // 25600
  int b = i / 400;
  float add = (1.f - p_gen[b]) * at_ws[i];
  atomicAdd(&final_out[(size_t)b*VEXTn + ebev[i]], add);
}

__global__ __launch_bounds__(256) void k_prevs(const float* __restrict__ prev_s, const float* __restrict__ h,
                                               float* __restrict__ o_prevs){
  int i = blockIdx.x*256 + threadIdx.x;   // 64*51*512 = 1,671,168
  int b = i / (51*512);
  int rem = i - b*51*512;
  int tau = rem >> 9, j = rem & 511;
  o_prevs[i] = (tau < 50) ? prev_s[((size_t)b*50 + tau)*512 + j] : h[b*512+j];
}

extern "C" void kernel_launch(void* const* d_in, const int* in_sizes, int n_in,
                              void* d_out, int out_size, void* d_ws, size_t ws_size,
                              hipStream_t stream)
{
  const float* x_t    = (const float*)d_in[0];
  const float* s_h    = (const float*)d_in[1];
  const float* s_c    = (const float*)d_in[2];
  const float* enc    = (const float*)d_in[3];
  const float* mask   = (const float*)d_in[4];
  const float* ct_e   = (const float*)d_in[5];
  const float* sumts  = (const float*)d_in[7];
  const float* prev_s = (const float*)d_in[8];
  const int*   ebev   = (const int*)d_in[9];
  const float* W_xc   = (const float*)d_in[10];
  const float* b_xc   = (const float*)d_in[11];
  const float* W_ih   = (const float*)d_in[12];
  const float* W_hh   = (const float*)d_in[13];
  const float* b_ih   = (const float*)d_in[14];
  const float* b_hh   = (const float*)d_in[15];
  const float* We_h   = (const float*)d_in[16];
  const float* We_s   = (const float*)d_in[17];
  const float* be_s   = (const float*)d_in[18];
  const float* ve     = (const float*)d_in[19];
  const float* Ws_h   = (const float*)d_in[20];
  const float* bs_h   = (const float*)d_in[21];
  const float* vs1    = (const float*)d_in[22];
  const float* vs2    = (const float*)d_in[23];
  const float* Wd_prev= (const float*)d_in[24];
  const float* Wd_s   = (const float*)d_in[25];
  const float* bd_s   = (const float*)d_in[26];
  const float* vd     = (const float*)d_in[27];
  const float* w_pg_em  = (const float*)d_in[28];
  const float* w_pg_cte = (const float*)d_in[29];
  const float* w_pg_ctd = (const float*)d_in[30];
  const float* w_pg_st  = (const float*)d_in[31];
  const float* b_pg_st  = (const float*)d_in[32];
  const float* W_V    = (const float*)d_in[33];
  const float* b_V    = (const float*)d_in[34];
  const float* W_V1   = (const float*)d_in[35];
  const float* b_V1   = (const float*)d_in[36];
  (void)in_sizes; (void)n_in; (void)out_size; (void)ws_size;

  float* out = (float*)d_out;
  float* o_final = out;                 // 64*50100 = 3,206,400
  float* o_h     = out + 3206400;       // 32768
  float* o_c     = out + 3239168;       // 32768
  float* o_cte   = out + 3271936;       // 65536
  float* o_au    = out + 3337472;       // 25600
  float* o_et2   = out + 3363072;       // 65536
  float* o_sumn  = out + 3428608;       // 25600
  float* o_prevs = out + 3454208;       // 1,671,168

  char* ws = (char*)d_ws;
  // ---- zeroed accumulators (contiguous, one memset) ----
  float* et_raw    = (float*)(ws + 0);         // 102400 B
  float* au_raw    = (float*)(ws + 102400);    // 102400 B
  float* et2_acc   = (float*)(ws + 204800);    // 262144 B
  float* x_acc     = (float*)(ws + 466944);    // 65536 B
  float* gates_acc = (float*)(ws + 532480);    // 524288 B
  float* qe_acc    = (float*)(ws + 1056768);   // 262144 B
  float* qd_acc    = (float*)(ws + 1318912);   // 131072 B
  float* ov_acc    = (float*)(ws + 1449984);   // 131072 B -> end 1581056
  // ---- scratch ----
  float* at_ws   = (float*)(ws + 1581056);     // 102400
  float* ct_d    = (float*)(ws + 1683456);     // 131072
  float* p_gen   = (float*)(ws + 1814528);     // 256
  float* tmp_ed  = (float*)(ws + 1900544);     // 6.55 MB  (shares region with logits, temporally disjoint)
  float* logits  = (float*)(ws + 1900544);     // 12.8 MB -> end 14700544
  unsigned short* out_vec_bf = (unsigned short*)(ws + 14700544);  // 65536 -> 14766080
  unsigned short* enc_bf  = (unsigned short*)(ws + 14780416);     // 52.4 MB -> 67209216
  unsigned short* W_V1T   = (unsigned short*)(ws + 14780416);     // 51.25 MB (after k_cte, enc_bf dead)
  unsigned short* Bt_bf   = (unsigned short*)(ws + 67209216);     // 4 MB -> 71403520

  hipMemsetAsync(ws, 0, 1581056, stream);
  k_conv_enc<<<25600, 256, 0, stream>>>(enc, enc_bf);
  k_transpose<<<dim3(32,32,2), 256, 0, stream>>>(We_h, Ws_h, Bt_bf);
  k_gemv_x<<<dim3(1,64,5), 256, 0, stream>>>(x_t, ct_e, W_xc, x_acc);
  k_gemv_gates<<<dim3(8,64,3), 256, 0, stream>>>(x_acc, b_xc, s_h, W_ih, W_hh, gates_acc);
  k_lstm_act<<<dim3(2,64), 256, 0, stream>>>(gates_acc, b_ih, b_hh, s_c, o_h, o_c);
  k_gemv_qe<<<dim3(4,64,4), 256, 0, stream>>>(o_h, o_c, We_s, qe_acc);
  k_gemv_qd<<<dim3(2,64,2), 256, 0, stream>>>(o_h, Wd_s, qd_acc);
  k_gemm_big<<<dim3(16,200), 256, 0, stream>>>(enc_bf, Bt_bf, qe_acc, be_s, bs_h, ve, vs1, vs2,
                                               et_raw, au_raw, et2_acc);
  k_attn_norm<<<64, 512, 0, stream>>>(et_raw, au_raw, et2_acc, sumts, mask, o_sumn, o_au, o_et2, at_ws);
  k_cte<<<dim3(4,64), 256, 0, stream>>>(enc_bf, at_ws, o_cte);
  // enc_bf dead from here; its region becomes W_V1T
  k_tr_v1<<<dim3(782,8), 256, 0, stream>>>(W_V1, W_V1T);
  k_ed<<<dim3(4,64), 256, 0, stream>>>(prev_s, Wd_prev, qd_acc, bd_s, vd, tmp_ed);
  k_ctd<<<64, 512, 0, stream>>>(tmp_ed, prev_s, ct_d);
  k_pgen<<<64, 256, 0, stream>>>(o_cte, ct_d, o_h, o_c, o_et2, w_pg_cte, w_pg_ctd, w_pg_st, w_pg_em, b_pg_st, p_gen);
  k_gemv_outvec<<<dim3(2,64,6), 256, 0, stream>>>(o_h, o_cte, ct_d, o_et2, W_V, ov_acc);
  k_outvec_fin<<<128, 256, 0, stream>>>(ov_acc, b_V, out_vec_bf);
  k_logits_mfma<<<782, 256, 0, stream>>>(out_vec_bf, W_V1T, b_V1, logits);
  k_softmax_final<<<64, 1024, 0, stream>>>(logits, p_gen, o_final);
  k_scatter<<<100, 256, 0, stream>>>(ebev, at_ws, p_gen, o_final);
  k_prevs<<<6528, 256, 0, stream>>>(prev_s, o_h, o_prevs);
}

// Round 5
// 908.736 us; speedup vs baseline: 1.9433x; 1.0203x over previous
//
#include <hip/hip_runtime.h>
#include <stdint.h>

#define Bn 64
#define Tn 400
#define Hn 512
#define En 256
#define Vn 50000
#define NOOVn 100
#define TPn 50
#define H2n 1024
#define VEXTn (Vn+NOOVn)  // 50100

typedef __bf16 bf16x8 __attribute__((ext_vector_type(8)));
typedef float  f32x4  __attribute__((ext_vector_type(4)));

__device__ __forceinline__ float sigf(float x){ return 1.0f/(1.0f+__expf(-x)); }
__device__ __forceinline__ float tanh_fast(float x){
  float e = __expf(2.0f*x);
  return (e-1.0f)/(e+1.0f);
}

__device__ __forceinline__ unsigned short f2bf(float f){
  union { float f; uint32_t u; } v; v.f = f;
  uint32_t r = v.u + 0x7FFFu + ((v.u >> 16) & 1u);
  return (unsigned short)(r >> 16);
}
__device__ __forceinline__ float bf2f(unsigned short s){
  union { uint32_t u; float f; } v; v.u = ((uint32_t)s) << 16;
  return v.f;
}

__device__ __forceinline__ void async16(const void* g, void* l){
  __builtin_amdgcn_global_load_lds((__attribute__((address_space(1))) void*)g,
                                   (__attribute__((address_space(3))) void*)l, 16, 0, 0);
}

// ---------------- conversions ----------------
__global__ __launch_bounds__(256) void k_conv_enc(const float* __restrict__ enc, unsigned short* __restrict__ out){
  int i = blockIdx.x*256 + threadIdx.x;
  const float4* e4 = (const float4*)enc;
  float4 v = e4[i];
  ushort4 r;
  r.x = f2bf(v.x); r.y = f2bf(v.y); r.z = f2bf(v.z); r.w = f2bf(v.w);
  ((ushort4*)out)[i] = r;
}

// Bt[n][k] = W[k][n], n<1024 from W1 (We_h), n>=1024 from W2 (Ws_h)
__global__ __launch_bounds__(256) void k_transpose(const float* __restrict__ W1, const float* __restrict__ W2,
                                                   unsigned short* __restrict__ Bt){
  const float* W = blockIdx.z ? W2 : W1;
  int nbase = blockIdx.z * 1024;
  __shared__ float tile[32][33];
  int k0 = blockIdx.y*32, n0 = blockIdx.x*32;
  int tx = threadIdx.x & 31, ty = threadIdx.x >> 5;  // ty 0..7
  for (int i = 0; i < 32; i += 8)
    tile[ty+i][tx] = W[(size_t)(k0+ty+i)*1024 + n0+tx];
  __syncthreads();
  for (int i = 0; i < 32; i += 8)
    Bt[(size_t)(nbase+n0+ty+i)*1024 + k0+tx] = f2bf(tile[tx][ty+i]);
}

// ---------------- split-K GEMV chain (M=64, fp32 atomics) ----------------
__global__ __launch_bounds__(256) void k_gemv_x(const float* __restrict__ x_t, const float* __restrict__ ct_e,
                                                const float* __restrict__ W_xc, float* __restrict__ x_acc){
  int n = threadIdx.x;
  int b = blockIdx.y;
  int k0 = blockIdx.z*256;        // z 0..4 (K=1280)
  float acc = 0.f;
  #pragma unroll 4
  for (int kk = 0; kk < 256; ++kk){
    int k = k0 + kk;
    float a = (k < 256) ? x_t[b*256+k] : ct_e[b*1024 + k - 256];
    acc += a * W_xc[(size_t)k*256 + n];
  }
  atomicAdd(&x_acc[b*256+n], acc);
}

__global__ __launch_bounds__(256) void k_gemv_gates(const float* __restrict__ x_acc, const float* __restrict__ b_xc,
                                                    const float* __restrict__ s_h,
                                                    const float* __restrict__ W_ih, const float* __restrict__ W_hh,
                                                    float* __restrict__ gates_acc){
  int n = blockIdx.x*256 + threadIdx.x;  // 0..2047
  int b = blockIdx.y;
  int k0 = blockIdx.z*256;               // z 0..2 (K=768)
  float acc = 0.f;
  #pragma unroll 4
  for (int kk = 0; kk < 256; ++kk){
    int k = k0 + kk;
    float a; const float* wrow;
    if (k < 256){ a = x_acc[b*256+k] + b_xc[k]; wrow = &W_ih[(size_t)k*2048]; }
    else        { a = s_h[b*512 + k-256];       wrow = &W_hh[(size_t)(k-256)*2048]; }
    acc += a * wrow[n];
  }
  atomicAdd(&gates_acc[(size_t)b*2048 + n], acc);
}

__global__ __launch_bounds__(256) void k_lstm_act(const float* __restrict__ gates_acc,
                                                  const float* __restrict__ b_ih, const float* __restrict__ b_hh,
                                                  const float* __restrict__ s_c,
                                                  float* __restrict__ h_out, float* __restrict__ c_out){
  int b = blockIdx.y;
  int j = blockIdx.x*256 + threadIdx.x;
  const float* g = &gates_acc[(size_t)b*2048];
  float gi = g[j]      + b_ih[j]      + b_hh[j];
  float gf = g[512+j]  + b_ih[512+j]  + b_hh[512+j];
  float gg = g[1024+j] + b_ih[1024+j] + b_hh[1024+j];
  float go = g[1536+j] + b_ih[1536+j] + b_hh[1536+j];
  float c = sigf(gf)*s_c[b*512+j] + sigf(gi)*tanh_fast(gg);
  float h = sigf(go)*tanh_fast(c);
  h_out[b*512+j] = h;
  c_out[b*512+j] = c;
}

__global__ __launch_bounds__(256) void k_gemv_qe(const float* __restrict__ h, const float* __restrict__ c,
                                                 const float* __restrict__ We_s, float* __restrict__ qe_acc){
  int n = blockIdx.x*256 + threadIdx.x;
  int b = blockIdx.y;
  int k0 = blockIdx.z*256;
  float acc = 0.f;
  #pragma unroll 4
  for (int kk = 0; kk < 256; ++kk){
    int k = k0 + kk;
    float a = (k < 512) ? h[b*512+k] : c[b*512 + k-512];
    acc += a * We_s[(size_t)k*1024 + n];
  }
  atomicAdd(&qe_acc[b*1024+n], acc);
}

__global__ __launch_bounds__(256) void k_gemv_qd(const float* __restrict__ h, const float* __restrict__ Wd_s,
                                                 float* __restrict__ qd_acc){
  int n = blockIdx.x*256 + threadIdx.x;
  int b = blockIdx.y;
  int k0 = blockIdx.z*256;
  float acc = 0.f;
  #pragma unroll 4
  for (int kk = 0; kk < 256; ++kk){
    int k = k0 + kk;
    acc += h[b*512+k] * Wd_s[(size_t)k*512 + n];
  }
  atomicAdd(&qd_acc[b*512+n], acc);
}

__global__ __launch_bounds__(256) void k_gemv_outvec(const float* __restrict__ h, const float* __restrict__ cte,
                                                     const float* __restrict__ ctd, const float* __restrict__ et2,
                                                     const float* __restrict__ W_V, float* __restrict__ ov_acc){
  int n = blockIdx.x*256 + threadIdx.x;
  int b = blockIdx.y;
  int z = blockIdx.z;
  const float* base;
  switch(z){
    case 0:  base = &h[b*512];        break;
    case 1:  base = &cte[b*1024];     break;
    case 2:  base = &cte[b*1024+512]; break;
    case 3:  base = &ctd[b*512];      break;
    case 4:  base = &et2[b*1024];     break;
    default: base = &et2[b*1024+512]; break;
  }
  const float* wrow = &W_V[(size_t)z*512*512];
  float acc = 0.f;
  #pragma unroll 4
  for (int kk = 0; kk < 512; ++kk)
    acc += base[kk] * wrow[(size_t)kk*512 + n];
  atomicAdd(&ov_acc[b*512+n], acc);
}

__global__ __launch_bounds__(256) void k_outvec_fin(const float* __restrict__ ov_acc, const float* __restrict__ b_V,
                                                    unsigned short* __restrict__ out_vec_bf){
  int i = blockIdx.x*256 + threadIdx.x;
  int j = i & 511;
  out_vec_bf[i] = f2bf(ov_acc[i] + b_V[j]);
}

// ---------------- the big fused dual-GEMM (m97 pattern + XOR-swizzled LDS) ----------------
__global__ __launch_bounds__(256,4) void k_gemm_big(
    const unsigned short* __restrict__ Abf,   // [25600][1024]
    const unsigned short* __restrict__ Btbf,  // [2048][1024]
    const float* __restrict__ q_e,
    const float* __restrict__ be_s,
    const float* __restrict__ bs_h, const float* __restrict__ ve,
    const float* __restrict__ vs1,  const float* __restrict__ vs2,
    float* __restrict__ et_raw, float* __restrict__ au_raw, float* __restrict__ et2_acc)
{
  __shared__ __align__(16) unsigned short As[128*64];
  __shared__ __align__(16) unsigned short Bs[128*64];
  __shared__ float bias2_s[2][128];
  __shared__ float vv_s[128];
  __shared__ float rowW_s[128];
  __shared__ unsigned char rowSel_s[128];

  const int tid = threadIdx.x;
  const int bn = blockIdx.x, bm = blockIdx.y;
  const int r0  = bm*128;
  const int n0g = bn*128;
  const bool etmode = (n0g < 1024);
  const int dbase = etmode ? n0g : (n0g - 1024);
  const int b_lo = r0/400;
  const int b_hi = min(b_lo+1, 63);
  const bool bcross = (r0/400) != ((r0+127)/400);

  if (tid < 128){
    int r = r0 + tid;
    int bb = r/400;
    rowSel_s[tid] = (unsigned char)(bb - b_lo);
    rowW_s[tid]   = vs2[r - bb*400];
    vv_s[tid]     = etmode ? ve[dbase+tid] : vs1[dbase+tid];
    bias2_s[0][tid] = etmode ? (q_e[b_lo*1024 + dbase + tid] + be_s[dbase+tid]) : bs_h[dbase+tid];
    bias2_s[1][tid] = etmode ? (q_e[b_hi*1024 + dbase + tid] + be_s[dbase+tid]) : bs_h[dbase+tid];
  }

  const int w = tid >> 6, lane = tid & 63;
  const int wm = w & 1, wn = w >> 1;
  const int lr = lane & 15, lq = lane >> 4;

  // XOR-swizzled staging: LDS slot (row, j) holds global chunk j ^ (row&7)
  const int srow = lane >> 3;
  const int c_g  = (lane & 7) ^ (srow & 7);      // swizzled global chunk for this lane
  const unsigned short* gA0 = Abf  + (size_t)(r0  + w*32 + srow)*1024 + c_g*8;
  const unsigned short* gB0 = Btbf + (size_t)(n0g + w*32 + srow)*1024 + c_g*8;
  unsigned short* lA0 = As + w*32*64;
  unsigned short* lB0 = Bs + w*32*64;

  f32x4 acc[4][4];
  #pragma unroll
  for (int i = 0; i < 4; ++i)
    #pragma unroll
    for (int j = 0; j < 4; ++j){ acc[i][j][0]=0.f; acc[i][j][1]=0.f; acc[i][j][2]=0.f; acc[i][j][3]=0.f; }

  for (int kt = 0; kt < 16; ++kt){
    __syncthreads();
    #pragma unroll
    for (int q = 0; q < 4; ++q){
      async16(gA0 + (size_t)q*8*1024 + kt*64, lA0 + q*512);
      async16(gB0 + (size_t)q*8*1024 + kt*64, lB0 + q*512);
    }
    __syncthreads();
    #pragma unroll
    for (int kk = 0; kk < 2; ++kk){
      const int slot8 = ((kk*4 + lq) ^ (lr & 7)) * 8;   // de-swizzled read
      bf16x8 a[4], b[4];
      #pragma unroll
      for (int i = 0; i < 4; ++i){
        a[i] = *(const bf16x8*)&As[(wm*64 + i*16 + lr)*64 + slot8];
        b[i] = *(const bf16x8*)&Bs[(wn*64 + i*16 + lr)*64 + slot8];
      }
      #pragma unroll
      for (int mt = 0; mt < 4; ++mt)
        #pragma unroll
        for (int nt = 0; nt < 4; ++nt)
          acc[mt][nt] = __builtin_amdgcn_mfma_f32_16x16x32_bf16(a[mt], b[nt], acc[mt][nt], 0, 0, 0);
    }
  }

  // ---- register epilogue ----
  float vvr[4], bias0[4], bias1[4];
  #pragma unroll
  for (int nt = 0; nt < 4; ++nt){
    int n = wn*64 + nt*16 + lr;
    vvr[nt]   = vv_s[n];
    bias0[nt] = bias2_s[0][n];
    bias1[nt] = bias2_s[1][n];
  }

  float rowdot[16];
  float colacc[4][2];
  #pragma unroll
  for (int nt = 0; nt < 4; ++nt){ colacc[nt][0]=0.f; colacc[nt][1]=0.f; }

  #pragma unroll
  for (int mt = 0; mt < 4; ++mt){
    #pragma unroll
    for (int v = 0; v < 4; ++v){
      int m = wm*64 + mt*16 + lq*4 + v;
      int sel = rowSel_s[m];
      float rw = rowW_s[m];
      float rd = 0.f;
      #pragma unroll
      for (int nt = 0; nt < 4; ++nt){
        float t = tanh_fast(acc[mt][nt][v] + (sel ? bias1[nt] : bias0[nt]));
        rd += t * vvr[nt];
        if (!etmode) colacc[nt][sel] += t * rw;
      }
      rowdot[mt*4+v] = rd;
    }
  }

  #pragma unroll
  for (int i = 0; i < 16; ++i){
    float s = rowdot[i];
    s += __shfl_xor(s,1); s += __shfl_xor(s,2); s += __shfl_xor(s,4); s += __shfl_xor(s,8);
    rowdot[i] = s;
  }
  if (lr == 0){
    float* dst = etmode ? et_raw : au_raw;
    #pragma unroll
    for (int i = 0; i < 16; ++i){
      int m = wm*64 + (i>>2)*16 + lq*4 + (i&3);
      atomicAdd(&dst[r0+m], rowdot[i]);
    }
  }

  if (!etmode){
    #pragma unroll
    for (int nt = 0; nt < 4; ++nt){
      #pragma unroll
      for (int s = 0; s < 2; ++s){
        float c = colacc[nt][s];
        c += __shfl_xor(c,16); c += __shfl_xor(c,32);
        if (lq == 0 && (s == 0 || bcross)){
          int n = wn*64 + nt*16 + lr;
          atomicAdd(&et2_acc[(b_lo+s)*1024 + dbase + n], c);
        }
      }
    }
  }
}

// ---------------- attention normalizations ----------------
__global__ __launch_bounds__(512) void k_attn_norm(const float* __restrict__ et_raw, const float* __restrict__ au_raw,
                                                   const float* __restrict__ et2_acc,
                                                   const float* __restrict__ sumts, const float* __restrict__ mask,
                                                   float* __restrict__ o_sumn, float* __restrict__ o_au,
                                                   float* __restrict__ o_et2, float* __restrict__ at_ws){
  int b = blockIdx.x, tid = threadIdx.x;
  __shared__ float red[512];
  float w = 0.f;
  if (tid < 400){
    float e  = __expf(et_raw[b*400+tid]);
    float st = sumts[b*400+tid];
    o_sumn[b*400+tid] = st + e;
    w = (e/st) * mask[b*400+tid];
  }
  red[tid] = w; __syncthreads();
  for (int s = 256; s > 0; s >>= 1){ if (tid < s) red[tid] += red[tid+s]; __syncthreads(); }
  float invw = 1.0f/red[0];
  __syncthreads();
  if (tid < 400) at_ws[b*400+tid] = w*invw;

  float a = 0.f;
  if (tid < 400) a = sigf(au_raw[b*400+tid]) * mask[b*400+tid];
  red[tid] = a; __syncthreads();
  for (int s = 256; s > 0; s >>= 1){ if (tid < s) red[tid] += red[tid+s]; __syncthreads(); }
  float inva = 1.0f/red[0];
  if (tid < 400) o_au[b*400+tid] = a*inva;

  for (int d = tid; d < 1024; d += 512) o_et2[b*1024+d] = sigf(et2_acc[b*1024+d]);
}

__global__ __launch_bounds__(256) void k_cte(const unsigned short* __restrict__ Abf, const float* __restrict__ at_ws,
                                             float* __restrict__ o_cte){
  int b = blockIdx.y;
  int d = blockIdx.x*256 + threadIdx.x;
  float acc = 0.f;
  for (int t = 0; t < 400; ++t)
    acc += at_ws[b*400+t] * bf2f(Abf[((size_t)(b*400+t))*1024 + d]);
  o_cte[b*1024+d] = acc;
}

// ---------------- intra-decoder attention ----------------
__global__ __launch_bounds__(256) void k_ed(const float* __restrict__ prev_s, const float* __restrict__ Wd_prev,
                                            const float* __restrict__ q_d, const float* __restrict__ bd_s,
                                            const float* __restrict__ vd, float* __restrict__ tmp_ed){
  int b = blockIdx.y;
  int j = (blockIdx.x & 1)*256 + threadIdx.x;
  int taub = (blockIdx.x >> 1)*25;
  float acc[25];
  #pragma unroll
  for (int t = 0; t < 25; ++t) acc[t] = 0.f;
  const float* ps = &prev_s[((size_t)b*50 + taub)*512];
  for (int k = 0; k < 512; ++k){
    float wv = Wd_prev[(size_t)k*512 + j];
    #pragma unroll
    for (int t = 0; t < 25; ++t) acc[t] += ps[(size_t)t*512 + k] * wv;
  }
  float qv = q_d[b*512+j] + bd_s[j], vdj = vd[j];
  #pragma unroll
  for (int t = 0; t < 25; ++t)
    tmp_ed[((size_t)b*50 + taub + t)*512 + j] = tanh_fast(acc[t] + qv) * vdj;
}

// ctd + p_gen fused (one block per b, 512 threads)
__global__ __launch_bounds__(512) void k_ctd_pgen(const float* __restrict__ tmp_ed, const float* __restrict__ prev_s,
                                                  const float* __restrict__ cte, const float* __restrict__ et2,
                                                  const float* __restrict__ h, const float* __restrict__ c,
                                                  const float* __restrict__ w_pg_cte, const float* __restrict__ w_pg_ctd,
                                                  const float* __restrict__ w_pg_st, const float* __restrict__ w_pg_em,
                                                  const float* __restrict__ b_pg_st,
                                                  float* __restrict__ ct_d, float* __restrict__ p_gen){
  int b = blockIdx.x, tid = threadIdx.x;
  __shared__ float ed_s[50];
  __shared__ float ad_s[50];
  __shared__ float red[512];
  if (tid < 400){
    int tau = tid >> 3, part = tid & 7;
    const float* tp = &tmp_ed[((size_t)b*50 + tau)*512 + part*64];
    float p = 0.f;
    for (int j = 0; j < 64; ++j) p += tp[j];
    p += __shfl_xor(p, 1); p += __shfl_xor(p, 2); p += __shfl_xor(p, 4);
    if (part == 0) ed_s[tau] = p;
  }
  __syncthreads();
  if (tid == 0){
    float mx = -1e30f;
    for (int t = 0; t < 50; ++t) mx = fmaxf(mx, ed_s[t]);
    float se = 0.f;
    for (int t = 0; t < 50; ++t){ float e = __expf(ed_s[t]-mx); ad_s[t] = e; se += e; }
    float inv = 1.f/se;
    for (int t = 0; t < 50; ++t) ad_s[t] *= inv;
  }
  __syncthreads();
  float acc = 0.f;
  for (int t = 0; t < 50; ++t) acc += ad_s[t]*prev_s[((size_t)b*50 + t)*512 + tid];
  ct_d[b*512+tid] = acc;

  // p_gen partials
  float s = acc*w_pg_ctd[tid] + h[b*512+tid]*w_pg_st[tid] + c[b*512+tid]*w_pg_st[512+tid];
  s += cte[b*1024+tid]*w_pg_cte[tid] + cte[b*1024+512+tid]*w_pg_cte[512+tid];
  s += et2[b*1024+tid]*w_pg_em[tid]  + et2[b*1024+512+tid]*w_pg_em[512+tid];
  red[tid] = s; __syncthreads();
  for (int k = 256; k > 0; k >>= 1){ if (tid < k) red[tid] += red[tid+k]; __syncthreads(); }
  if (tid == 0) p_gen[b] = sigf(red[0] + b_pg_st[0]);
}

// ---------------- logits MFMA with fused W_V1 transpose+convert ----------------
// logits[64][50000] = out_vec_bf[64][512] @ W_V1; B staged per-tile from fp32 [k][n]
// into padded LDS [n][k] (pitch 72 -> uniform bank spread).
__global__ __launch_bounds__(256,4) void k_logits_mfma(const unsigned short* __restrict__ Abf,  // [64][512] bf16
                                                       const float* __restrict__ W_V1,          // [512][50000] fp32
                                                       const float* __restrict__ b_V1, float* __restrict__ logits){
  __shared__ __align__(16) unsigned short As[64][72];
  __shared__ __align__(16) unsigned short Bs[64][72];
  const int tid = threadIdx.x;
  const int n0 = blockIdx.x*64;
  const int w = tid >> 6, lane = tid & 63;
  const int lr = lane & 15, lq = lane >> 4;

  const int am = tid >> 2, ac = tid & 3;        // A staging: m, chunk
  const int sn = tid & 63, skg = tid >> 6;      // B staging: n, k-group
  const int bnc = (n0 + sn < Vn) ? (n0 + sn) : (Vn - 1);

  f32x4 acc[4];
  #pragma unroll
  for (int i = 0; i < 4; ++i){ acc[i][0]=0.f; acc[i][1]=0.f; acc[i][2]=0.f; acc[i][3]=0.f; }

  for (int kt = 0; kt < 8; ++kt){
    const int k0 = kt*64;
    __syncthreads();
    // A tile: bf16, coalesced uint4 loads -> padded LDS
    #pragma unroll
    for (int s = 0; s < 2; ++s){
      uint4 av = *(const uint4*)&Abf[am*512 + k0 + (ac + 4*s)*8];
      *(uint4*)&As[am][(ac + 4*s)*8] = av;
    }
    // B tile: fp32 [k][n] -> bf16 LDS [n][k]
    #pragma unroll
    for (int jq = 0; jq < 4; ++jq){
      int kb = k0 + skg*16 + jq*4;
      float f0 = W_V1[(size_t)(kb+0)*Vn + bnc];
      float f1 = W_V1[(size_t)(kb+1)*Vn + bnc];
      float f2 = W_V1[(size_t)(kb+2)*Vn + bnc];
      float f3 = W_V1[(size_t)(kb+3)*Vn + bnc];
      ushort4 u; u.x = f2bf(f0); u.y = f2bf(f1); u.z = f2bf(f2); u.w = f2bf(f3);
      *(ushort4*)&Bs[sn][skg*16 + jq*4] = u;
    }
    __syncthreads();
    #pragma unroll
    for (int kk = 0; kk < 2; ++kk){
      bf16x8 a[4], b;
      #pragma unroll
      for (int i = 0; i < 4; ++i)
        a[i] = *(const bf16x8*)&As[i*16 + lr][kk*32 + lq*8];
      b = *(const bf16x8*)&Bs[w*16 + lr][kk*32 + lq*8];
      #pragma unroll
      for (int mt = 0; mt < 4; ++mt)
        acc[mt] = __builtin_amdgcn_mfma_f32_16x16x32_bf16(a[mt], b, acc[mt], 0, 0, 0);
    }
  }

  int n = n0 + w*16 + lr;
  if (n < Vn){
    float bb = b_V1[n];
    #pragma unroll
    for (int mt = 0; mt < 4; ++mt)
      #pragma unroll
      for (int v = 0; v < 4; ++v){
        int m = mt*16 + lq*4 + v;
        logits[(size_t)m*Vn + n] = acc[mt][v] + bb;
      }
  }
}

// softmax + pointer-scatter fused (block b owns row b)
__global__ __launch_bounds__(1024) void k_softmax_scatter(const float* __restrict__ logits, const float* __restrict__ p_gen,
                                                          const int* __restrict__ ebev, const float* __restrict__ at_ws,
                                                          float* __restrict__ final_out){
  int b = blockIdx.x, tid = threadIdx.x;
  __shared__ float red[1024];
  const float* lrow = &logits[(size_t)b*Vn];
  float mx = -1e30f;
  for (int v = tid; v < Vn; v += 1024) mx = fmaxf(mx, lrow[v]);
  red[tid] = mx; __syncthreads();
  for (int s = 512; s > 0; s >>= 1){ if (tid < s) red[tid] = fmaxf(red[tid], red[tid+s]); __syncthreads(); }
  mx = red[0]; __syncthreads();
  float se = 0.f;
  for (int v = tid; v < Vn; v += 1024) se += __expf(lrow[v]-mx);
  red[tid] = se; __syncthreads();
  for (int s = 512; s > 0; s >>= 1){ if (tid < s) red[tid] += red[tid+s]; __syncthreads(); }
  float pgb = p_gen[b];
  float scale = pgb/red[0];
  float* frow = &final_out[(size_t)b*VEXTn];
  for (int v = tid; v < Vn; v += 1024) frow[v] = __expf(lrow[v]-mx)*scale;
  for (int v = Vn+tid; v < VEXTn; v += 1024) frow[v] = 0.f;
  __syncthreads();
  if (tid < 400){
    float add = (1.f - pgb) * at_ws[b*400+tid];
    atomicAdd(&frow[ebev[b*400+tid]], add);
  }
}

__global__ __launch_bounds__(256) void k_prevs(const float* __restrict__ prev_s, const float* __restrict__ h,
                                               float* __restrict__ o_prevs){
  int i = blockIdx.x*256 + threadIdx.x;
  int b = i / (51*512);
  int rem = i - b*51*512;
  int tau = rem >> 9, j = rem & 511;
  o_prevs[i] = (tau < 50) ? prev_s[((size_t)b*50 + tau)*512 + j] : h[b*512+j];
}

extern "C" void kernel_launch(void* const* d_in, const int* in_sizes, int n_in,
                              void* d_out, int out_size, void* d_ws, size_t ws_size,
                              hipStream_t stream)
{
  const float* x_t    = (const float*)d_in[0];
  const float* s_h    = (const float*)d_in[1];
  const float* s_c    = (const float*)d_in[2];
  const float* enc    = (const float*)d_in[3];
  const float* mask   = (const float*)d_in[4];
  const float* ct_e   = (const float*)d_in[5];
  const float* sumts  = (const float*)d_in[7];
  const float* prev_s = (const float*)d_in[8];
  const int*   ebev   = (const int*)d_in[9];
  const float* W_xc   = (const float*)d_in[10];
  const float* b_xc   = (const float*)d_in[11];
  const float* W_ih   = (const float*)d_in[12];
  const float* W_hh   = (const float*)d_in[13];
  const float* b_ih   = (const float*)d_in[14];
  const float* b_hh   = (const float*)d_in[15];
  const float* We_h   = (const float*)d_in[16];
  const float* We_s   = (const float*)d_in[17];
  const float* be_s   = (const float*)d_in[18];
  const float* ve     = (const float*)d_in[19];
  const float* Ws_h   = (const float*)d_in[20];
  const float* bs_h   = (const float*)d_in[21];
  const float* vs1    = (const float*)d_in[22];
  const float* vs2    = (const float*)d_in[23];
  const float* Wd_prev= (const float*)d_in[24];
  const float* Wd_s   = (const float*)d_in[25];
  const float* bd_s   = (const float*)d_in[26];
  const float* vd     = (const float*)d_in[27];
  const float* w_pg_em  = (const float*)d_in[28];
  const float* w_pg_cte = (const float*)d_in[29];
  const float* w_pg_ctd = (const float*)d_in[30];
  const float* w_pg_st  = (const float*)d_in[31];
  const float* b_pg_st  = (const float*)d_in[32];
  const float* W_V    = (const float*)d_in[33];
  const float* b_V    = (const float*)d_in[34];
  const float* W_V1   = (const float*)d_in[35];
  const float* b_V1   = (const float*)d_in[36];
  (void)in_sizes; (void)n_in; (void)out_size; (void)ws_size;

  float* out = (float*)d_out;
  float* o_final = out;
  float* o_h     = out + 3206400;
  float* o_c     = out + 3239168;
  float* o_cte   = out + 3271936;
  float* o_au    = out + 3337472;
  float* o_et2   = out + 3363072;
  float* o_sumn  = out + 3428608;
  float* o_prevs = out + 3454208;

  char* ws = (char*)d_ws;
  // zeroed accumulators
  float* et_raw    = (float*)(ws + 0);
  float* au_raw    = (float*)(ws + 102400);
  float* et2_acc   = (float*)(ws + 204800);
  float* x_acc     = (float*)(ws + 466944);
  float* gates_acc = (float*)(ws + 532480);
  float* qe_acc    = (float*)(ws + 1056768);
  float* qd_acc    = (float*)(ws + 1318912);
  float* ov_acc    = (float*)(ws + 1449984);    // end 1581056
  // scratch
  float* at_ws   = (float*)(ws + 1581056);
  float* ct_d    = (float*)(ws + 1683456);
  float* p_gen   = (float*)(ws + 1814528);
  float* tmp_ed  = (float*)(ws + 1900544);      // 6.55 MB (shares region with logits)
  float* logits  = (float*)(ws + 1900544);      // 12.8 MB -> end 14700544
  unsigned short* out_vec_bf = (unsigned short*)(ws + 14700544);
  unsigned short* enc_bf  = (unsigned short*)(ws + 14780416);   // 52.4 MB
  unsigned short* Bt_bf   = (unsigned short*)(ws + 67209216);   // 4 MB

  hipMemsetAsync(ws, 0, 1581056, stream);
  k_conv_enc<<<25600, 256, 0, stream>>>(enc, enc_bf);
  k_transpose<<<dim3(32,32,2), 256, 0, stream>>>(We_h, Ws_h, Bt_bf);
  k_gemv_x<<<dim3(1,64,5), 256, 0, stream>>>(x_t, ct_e, W_xc, x_acc);
  k_gemv_gates<<<dim3(8,64,3), 256, 0, stream>>>(x_acc, b_xc, s_h, W_ih, W_hh, gates_acc);
  k_lstm_act<<<dim3(2,64), 256, 0, stream>>>(gates_acc, b_ih, b_hh, s_c, o_h, o_c);
  k_gemv_qe<<<dim3(4,64,4), 256, 0, stream>>>(o_h, o_c, We_s, qe_acc);
  k_gemv_qd<<<dim3(2,64,2), 256, 0, stream>>>(o_h, Wd_s, qd_acc);
  k_gemm_big<<<dim3(16,200), 256, 0, stream>>>(enc_bf, Bt_bf, qe_acc, be_s, bs_h, ve, vs1, vs2,
                                               et_raw, au_raw, et2_acc);
  k_attn_norm<<<64, 512, 0, stream>>>(et_raw, au_raw, et2_acc, sumts, mask, o_sumn, o_au, o_et2, at_ws);
  k_cte<<<dim3(4,64), 256, 0, stream>>>(enc_bf, at_ws, o_cte);
  k_ed<<<dim3(4,64), 256, 0, stream>>>(prev_s, Wd_prev, qd_acc, bd_s, vd, tmp_ed);
  k_ctd_pgen<<<64, 512, 0, stream>>>(tmp_ed, prev_s, o_cte, o_et2, o_h, o_c,
                                     w_pg_cte, w_pg_ctd, w_pg_st, w_pg_em, b_pg_st, ct_d, p_gen);
  k_gemv_outvec<<<dim3(2,64,6), 256, 0, stream>>>(o_h, o_cte, ct_d, o_et2, W_V, ov_acc);
  k_outvec_fin<<<128, 256, 0, stream>>>(ov_acc, b_V, out_vec_bf);
  k_logits_mfma<<<782, 256, 0, stream>>>(out_vec_bf, W_V1, b_V1, logits);
  k_softmax_scatter<<<64, 1024, 0, stream>>>(logits, p_gen, ebev, at_ws, o_final);
  k_prevs<<<6528, 256, 0, stream>>>(prev_s, o_h, o_prevs);
}